// Round 4
// baseline (18209.285 us; speedup 1.0000x reference)
//
#include <hip/hip_runtime.h>
#include <cstdint>
#include <cstddef>

#define BN_EPS 1e-5f

__device__ __forceinline__ float sigf(float x) {
    return 1.0f / (1.0f + __expf(-x));
}
__device__ __forceinline__ float tanhfast(float x) {
    return 2.0f / (1.0f + __expf(-2.0f * x)) - 1.0f;
}
__device__ __forceinline__ unsigned bfr(float x) {  // f32 -> bf16 bits (RNE)
    unsigned u = __float_as_uint(x);
    return (u + 0x7fffu + ((u >> 16) & 1u)) >> 16;
}

// ---------------- conv1 + BN + ReLU : x[B,T,9] -> y1[B,32,T] ----------------
__global__ __launch_bounds__(256) void k_conv1(
    const float* __restrict__ x, const float* __restrict__ w,
    const float* __restrict__ g, const float* __restrict__ bb,
    const float* __restrict__ m, const float* __restrict__ v,
    float* __restrict__ y1, int B, int T)
{
    const int TT = 256;
    __shared__ float xs[(TT + 6) * 9];
    const int b = blockIdx.y;
    const int t0 = blockIdx.x * TT;
    const int tid = threadIdx.x;

    for (int idx = tid; idx < (TT + 6) * 9; idx += 256) {
        int row = idx / 9, col = idx - row * 9;
        int tg = t0 - 3 + row;
        xs[idx] = (tg >= 0 && tg < T) ? x[((size_t)b * T + tg) * 9 + col] : 0.0f;
    }
    __syncthreads();

    float xv[63];
#pragma unroll
    for (int k = 0; k < 7; ++k)
#pragma unroll
        for (int ci = 0; ci < 9; ++ci)
            xv[k * 9 + ci] = xs[(tid + k) * 9 + ci];

    const int t = t0 + tid;
    for (int co = 0; co < 32; ++co) {
        float acc = 0.0f;
#pragma unroll
        for (int ci = 0; ci < 9; ++ci)
#pragma unroll
            for (int k = 0; k < 7; ++k)
                acc += xv[k * 9 + ci] * w[(co * 9 + ci) * 7 + k];
        float sc = g[co] / sqrtf(v[co] + BN_EPS);
        float bf = bb[co] - m[co] * sc;
        float o = acc * sc + bf;
        y1[((size_t)b * 32 + co) * T + t] = o > 0.0f ? o : 0.0f;
    }
}

// ---------------- conv2 + BN + ReLU : y1[B,32,T] -> y2[B,64,T] --------------
__global__ __launch_bounds__(256) void k_conv2(
    const float* __restrict__ y1, const float* __restrict__ w,
    const float* __restrict__ g, const float* __restrict__ bb,
    const float* __restrict__ m, const float* __restrict__ v,
    float* __restrict__ y2, int B, int T)
{
    const int TT = 256;
    __shared__ float ys[32 * (TT + 6)];
    const int b = blockIdx.y;
    const int t0 = blockIdx.x * TT;
    const int tid = threadIdx.x;

    for (int idx = tid; idx < 32 * (TT + 6); idx += 256) {
        int ci = idx / (TT + 6), i = idx - ci * (TT + 6);
        int tg = t0 - 3 + i;
        ys[idx] = (tg >= 0 && tg < T) ? y1[((size_t)b * 32 + ci) * T + tg] : 0.0f;
    }
    __syncthreads();

    float acc[64];
#pragma unroll
    for (int co = 0; co < 64; ++co) acc[co] = 0.0f;

    for (int ci = 0; ci < 32; ++ci) {
        float yw[7];
#pragma unroll
        for (int k = 0; k < 7; ++k) yw[k] = ys[ci * (TT + 6) + tid + k];
#pragma unroll
        for (int co = 0; co < 64; ++co)
#pragma unroll
            for (int k = 0; k < 7; ++k)
                acc[co] += yw[k] * w[(co * 32 + ci) * 7 + k];
    }

    const int t = t0 + tid;
    for (int co = 0; co < 64; ++co) {
        float sc = g[co] / sqrtf(v[co] + BN_EPS);
        float bf = bb[co] - m[co] * sc;
        float o = acc[co] * sc + bf;
        y2[((size_t)b * 64 + co) * T + t] = o > 0.0f ? o : 0.0f;
    }
}

// ------------- conv3 + BN + ReLU : y2[B,64,T] -> feat[B,T,128] --------------
__global__ __launch_bounds__(256) void k_conv3(
    const float* __restrict__ y2, const float* __restrict__ w,
    const float* __restrict__ g, const float* __restrict__ bb,
    const float* __restrict__ m, const float* __restrict__ v,
    float* __restrict__ feat, int B, int T)
{
    const int TT = 128;
    __shared__ float ys[64 * (TT + 6)];
    const int b = blockIdx.y;
    const int t0 = blockIdx.x * TT;
    const int tid = threadIdx.x;
    const int tl = tid & 127;
    const int half = __builtin_amdgcn_readfirstlane(tid >> 7);  // wave-uniform

    for (int idx = tid; idx < 64 * (TT + 6); idx += 256) {
        int ci = idx / (TT + 6), i = idx - ci * (TT + 6);
        int tg = t0 - 3 + i;
        ys[idx] = (tg >= 0 && tg < T) ? y2[((size_t)b * 64 + ci) * T + tg] : 0.0f;
    }
    __syncthreads();

    float acc[64];
#pragma unroll
    for (int q = 0; q < 64; ++q) acc[q] = 0.0f;

    for (int ci = 0; ci < 64; ++ci) {
        float yw[7];
#pragma unroll
        for (int k = 0; k < 7; ++k) yw[k] = ys[ci * (TT + 6) + tl + k];
#pragma unroll
        for (int q = 0; q < 64; ++q)
#pragma unroll
            for (int k = 0; k < 7; ++k)
                acc[q] += yw[k] * w[((half * 64 + q) * 64 + ci) * 7 + k];
    }

    const int t = t0 + tl;
    for (int q = 0; q < 64; ++q) {
        int co = half * 64 + q;
        float sc = g[co] / sqrtf(v[co] + BN_EPS);
        float bf = bb[co] - m[co] * sc;
        float o = acc[q] * sc + bf;
        feat[((size_t)b * T + t) * 128 + co] = o > 0.0f ? o : 0.0f;
    }
}

// --------------------------- reversed-time LSTM -----------------------------
// 512 threads = (j2 in [0,128)) x (k-quarter q in [0,4)).
// Thread (j2,q): partial dot over k in [32q,32q+32) for gates {j2+128g}.
// Weights MUST live in VGPRs across all 4096 steps (~220 regs/thread).
// amdgpu_waves_per_eu(2,2) pins the regalloc occupancy target at 2 waves/SIMD
// (256-VGPR budget); the empty asm on each element makes the loaded values
// opaque so they cannot be rematerialized/folded back into the t-loop.
// (Rounds 2-3: compiler chose 128 VGPRs and re-fetched ~768B/thread/step ->
// L2-BW-bound at ~2.9us/step. That was the entire bottleneck.)
__global__ __launch_bounds__(512)
__attribute__((amdgpu_waves_per_eu(2, 2)))
void k_lstm2(
    const float* __restrict__ feat, const float* __restrict__ w_ih,
    const float* __restrict__ w_hh, const float* __restrict__ b_ih,
    const float* __restrict__ b_hh, float* __restrict__ out, int T)
{
    __shared__ __align__(16) float h_sh[128];
    __shared__ __align__(16) float x_sh[2][128];
    __shared__ float p_sh[16][128];  // [q*4+g][j2]

    const int b = blockIdx.x;
    const int tid = threadIdx.x;
    const int j2 = tid & 127;
    const int q = tid >> 7;  // wave-uniform (waves 2q, 2q+1)

    // --- load weights into registers ---
    float wh[4][32];          // W_hh[j2+128g][32q+kk], f32 (128 VGPRs)
    unsigned wiu[4][16];      // W_ih same slice, bf16 pairs packed (64 VGPRs)
#pragma unroll
    for (int g = 0; g < 4; ++g) {
        const float* hr = w_hh + (size_t)(j2 + 128 * g) * 128 + 32 * q;
        const float* ir = w_ih + (size_t)(j2 + 128 * g) * 128 + 32 * q;
#pragma unroll
        for (int kk = 0; kk < 32; kk += 4) {
            float4 h4 = *reinterpret_cast<const float4*>(hr + kk);
            wh[g][kk + 0] = h4.x; wh[g][kk + 1] = h4.y;
            wh[g][kk + 2] = h4.z; wh[g][kk + 3] = h4.w;
            float4 i4 = *reinterpret_cast<const float4*>(ir + kk);
            wiu[g][kk / 2]     = (bfr(i4.y) << 16) | bfr(i4.x);
            wiu[g][kk / 2 + 1] = (bfr(i4.w) << 16) | bfr(i4.z);
        }
    }
    // pin: values become opaque asm outputs -> no remat back into the loop
#pragma unroll
    for (int g = 0; g < 4; ++g) {
#pragma unroll
        for (int i = 0; i < 32; ++i) asm volatile("" : "+v"(wh[g][i]));
#pragma unroll
        for (int i = 0; i < 16; ++i) asm volatile("" : "+v"(wiu[g][i]));
    }

    float bias[4];
#pragma unroll
    for (int g = 0; g < 4; ++g)
        bias[g] = b_ih[j2 + 128 * g] + b_hh[j2 + 128 * g];

    // --- init state, stage x for first two steps ---
    float cst = 0.0f;
    if (tid < 128) h_sh[tid] = 0.0f;
    float xnv = 0.0f;
    if (tid < 128) {
        x_sh[0][tid] = feat[((size_t)b * T + (T - 1)) * 128 + tid];
        if (T >= 2) xnv = feat[((size_t)b * T + (T - 2)) * 128 + tid];
    }
    __syncthreads();

    int cur = 0;
    for (int t = T - 1; t >= 0; --t) {
        // ---- phase 1: partial dots (all 512 threads) ----
        float acc[4] = {0.0f, 0.0f, 0.0f, 0.0f};
        const float4* hv = reinterpret_cast<const float4*>(h_sh) + 8 * q;
        const float4* xv = reinterpret_cast<const float4*>(x_sh[cur]) + 8 * q;
#pragma unroll
        for (int k4 = 0; k4 < 8; ++k4) {
            float4 h4 = hv[k4];
            float4 x4 = xv[k4];
#pragma unroll
            for (int g = 0; g < 4; ++g) {
                float a = acc[g];
                a += h4.x * wh[g][4 * k4 + 0];
                a += h4.y * wh[g][4 * k4 + 1];
                a += h4.z * wh[g][4 * k4 + 2];
                a += h4.w * wh[g][4 * k4 + 3];
                unsigned u0 = wiu[g][2 * k4], u1 = wiu[g][2 * k4 + 1];
                a += x4.x * __uint_as_float(u0 << 16);
                a += x4.y * __uint_as_float(u0 & 0xffff0000u);
                a += x4.z * __uint_as_float(u1 << 16);
                a += x4.w * __uint_as_float(u1 & 0xffff0000u);
                acc[g] = a;
            }
        }
#pragma unroll
        for (int g = 0; g < 4; ++g)
            p_sh[q * 4 + g][j2] = acc[g];
        __syncthreads();  // A: partials visible

        // ---- phase 2: reduce + pointwise (threads j<128) ----
        if (tid < 128) {
            float gi = bias[0] + ((p_sh[0][tid] + p_sh[4][tid]) + (p_sh[8][tid]  + p_sh[12][tid]));
            float gf = bias[1] + ((p_sh[1][tid] + p_sh[5][tid]) + (p_sh[9][tid]  + p_sh[13][tid]));
            float gg = bias[2] + ((p_sh[2][tid] + p_sh[6][tid]) + (p_sh[10][tid] + p_sh[14][tid]));
            float go = bias[3] + ((p_sh[3][tid] + p_sh[7][tid]) + (p_sh[11][tid] + p_sh[15][tid]));
            cst = sigf(gf) * cst + sigf(gi) * tanhfast(gg);
            float h = sigf(go) * tanhfast(cst);
            h_sh[tid] = h;
            out[((size_t)b * T + t) * 128 + tid] = h;
            x_sh[cur ^ 1][tid] = xnv;  // x for step t-1
            xnv = (t >= 2) ? feat[((size_t)b * T + (t - 2)) * 128 + tid] : 0.0f;
        }
        cur ^= 1;
        __syncthreads();  // B: h_sh / x_sh ready for next step
    }
}

extern "C" void kernel_launch(void* const* d_in, const int* in_sizes, int n_in,
                              void* d_out, int out_size, void* d_ws, size_t ws_size,
                              hipStream_t stream)
{
    const float* x    = (const float*)d_in[0];
    const float* c1w  = (const float*)d_in[1];
    const float* bn1g = (const float*)d_in[2];
    const float* bn1b = (const float*)d_in[3];
    const float* bn1m = (const float*)d_in[4];
    const float* bn1v = (const float*)d_in[5];
    const float* c2w  = (const float*)d_in[6];
    const float* bn2g = (const float*)d_in[7];
    const float* bn2b = (const float*)d_in[8];
    const float* bn2m = (const float*)d_in[9];
    const float* bn2v = (const float*)d_in[10];
    const float* c3w  = (const float*)d_in[11];
    const float* bn3g = (const float*)d_in[12];
    const float* bn3b = (const float*)d_in[13];
    const float* bn3m = (const float*)d_in[14];
    const float* bn3v = (const float*)d_in[15];
    const float* w_ih = (const float*)d_in[16];
    const float* w_hh = (const float*)d_in[17];
    const float* b_ih = (const float*)d_in[18];
    const float* b_hh = (const float*)d_in[19];
    float* out = (float*)d_out;

    const int B = 64, T = 4096;
    char* ws = (char*)d_ws;
    const size_t sz_y1 = (size_t)B * 32 * T * 4;   // 32 MB
    const size_t sz_y2 = (size_t)B * 64 * T * 4;   // 64 MB

    float* y1   = (float*)ws;
    float* y2   = (float*)(ws + sz_y1);
    float* feat = (float*)(ws + sz_y1 + sz_y2);

    k_conv1<<<dim3(T / 256, B), 256, 0, stream>>>(x, c1w, bn1g, bn1b, bn1m, bn1v, y1, B, T);
    k_conv2<<<dim3(T / 256, B), 256, 0, stream>>>(y1, c2w, bn2g, bn2b, bn2m, bn2v, y2, B, T);
    k_conv3<<<dim3(T / 128, B), 256, 0, stream>>>(y2, c3w, bn3g, bn3b, bn3m, bn3v, feat, B, T);

    k_lstm2<<<dim3(B), 512, 0, stream>>>(feat, w_ih, w_hh, b_ih, b_hh, out, T);
}

// Round 5
// 15488.403 us; speedup vs baseline: 1.1757x; 1.1757x over previous
//
#include <hip/hip_runtime.h>
#include <cstdint>
#include <cstddef>

#define BN_EPS 1e-5f

__device__ __forceinline__ float sigf(float x) {
    return 1.0f / (1.0f + __expf(-x));
}
__device__ __forceinline__ float tanhfast(float x) {
    return 2.0f / (1.0f + __expf(-2.0f * x)) - 1.0f;
}
__device__ __forceinline__ unsigned bfr(float x) {  // f32 -> bf16 bits (RNE)
    unsigned u = __float_as_uint(x);
    return (u + 0x7fffu + ((u >> 16) & 1u)) >> 16;
}

// ---------------- conv1 + BN + ReLU : x[B,T,9] -> y1[B,32,T] ----------------
__global__ __launch_bounds__(256) void k_conv1(
    const float* __restrict__ x, const float* __restrict__ w,
    const float* __restrict__ g, const float* __restrict__ bb,
    const float* __restrict__ m, const float* __restrict__ v,
    float* __restrict__ y1, int B, int T)
{
    const int TT = 256;
    __shared__ float xs[(TT + 6) * 9];
    const int b = blockIdx.y;
    const int t0 = blockIdx.x * TT;
    const int tid = threadIdx.x;

    for (int idx = tid; idx < (TT + 6) * 9; idx += 256) {
        int row = idx / 9, col = idx - row * 9;
        int tg = t0 - 3 + row;
        xs[idx] = (tg >= 0 && tg < T) ? x[((size_t)b * T + tg) * 9 + col] : 0.0f;
    }
    __syncthreads();

    float xv[63];
#pragma unroll
    for (int k = 0; k < 7; ++k)
#pragma unroll
        for (int ci = 0; ci < 9; ++ci)
            xv[k * 9 + ci] = xs[(tid + k) * 9 + ci];

    const int t = t0 + tid;
    for (int co = 0; co < 32; ++co) {
        float acc = 0.0f;
#pragma unroll
        for (int ci = 0; ci < 9; ++ci)
#pragma unroll
            for (int k = 0; k < 7; ++k)
                acc += xv[k * 9 + ci] * w[(co * 9 + ci) * 7 + k];
        float sc = g[co] / sqrtf(v[co] + BN_EPS);
        float bf = bb[co] - m[co] * sc;
        float o = acc * sc + bf;
        y1[((size_t)b * 32 + co) * T + t] = o > 0.0f ? o : 0.0f;
    }
}

// ---------------- conv2 + BN + ReLU : y1[B,32,T] -> y2[B,64,T] --------------
__global__ __launch_bounds__(256) void k_conv2(
    const float* __restrict__ y1, const float* __restrict__ w,
    const float* __restrict__ g, const float* __restrict__ bb,
    const float* __restrict__ m, const float* __restrict__ v,
    float* __restrict__ y2, int B, int T)
{
    const int TT = 256;
    __shared__ float ys[32 * (TT + 6)];
    const int b = blockIdx.y;
    const int t0 = blockIdx.x * TT;
    const int tid = threadIdx.x;

    for (int idx = tid; idx < 32 * (TT + 6); idx += 256) {
        int ci = idx / (TT + 6), i = idx - ci * (TT + 6);
        int tg = t0 - 3 + i;
        ys[idx] = (tg >= 0 && tg < T) ? y1[((size_t)b * 32 + ci) * T + tg] : 0.0f;
    }
    __syncthreads();

    float acc[64];
#pragma unroll
    for (int co = 0; co < 64; ++co) acc[co] = 0.0f;

    for (int ci = 0; ci < 32; ++ci) {
        float yw[7];
#pragma unroll
        for (int k = 0; k < 7; ++k) yw[k] = ys[ci * (TT + 6) + tid + k];
#pragma unroll
        for (int co = 0; co < 64; ++co)
#pragma unroll
            for (int k = 0; k < 7; ++k)
                acc[co] += yw[k] * w[(co * 32 + ci) * 7 + k];
    }

    const int t = t0 + tid;
    for (int co = 0; co < 64; ++co) {
        float sc = g[co] / sqrtf(v[co] + BN_EPS);
        float bf = bb[co] - m[co] * sc;
        float o = acc[co] * sc + bf;
        y2[((size_t)b * 64 + co) * T + t] = o > 0.0f ? o : 0.0f;
    }
}

// ------------- conv3 + BN + ReLU : y2[B,64,T] -> feat[B,T,128] --------------
__global__ __launch_bounds__(256) void k_conv3(
    const float* __restrict__ y2, const float* __restrict__ w,
    const float* __restrict__ g, const float* __restrict__ bb,
    const float* __restrict__ m, const float* __restrict__ v,
    float* __restrict__ feat, int B, int T)
{
    const int TT = 128;
    __shared__ float ys[64 * (TT + 6)];
    const int b = blockIdx.y;
    const int t0 = blockIdx.x * TT;
    const int tid = threadIdx.x;
    const int tl = tid & 127;
    const int half = __builtin_amdgcn_readfirstlane(tid >> 7);  // wave-uniform

    for (int idx = tid; idx < 64 * (TT + 6); idx += 256) {
        int ci = idx / (TT + 6), i = idx - ci * (TT + 6);
        int tg = t0 - 3 + i;
        ys[idx] = (tg >= 0 && tg < T) ? y2[((size_t)b * 64 + ci) * T + tg] : 0.0f;
    }
    __syncthreads();

    float acc[64];
#pragma unroll
    for (int q = 0; q < 64; ++q) acc[q] = 0.0f;

    for (int ci = 0; ci < 64; ++ci) {
        float yw[7];
#pragma unroll
        for (int k = 0; k < 7; ++k) yw[k] = ys[ci * (TT + 6) + tl + k];
#pragma unroll
        for (int q = 0; q < 64; ++q)
#pragma unroll
            for (int k = 0; k < 7; ++k)
                acc[q] += yw[k] * w[((half * 64 + q) * 64 + ci) * 7 + k];
    }

    const int t = t0 + tl;
    for (int q = 0; q < 64; ++q) {
        int co = half * 64 + q;
        float sc = g[co] / sqrtf(v[co] + BN_EPS);
        float bf = bb[co] - m[co] * sc;
        float o = acc[q] * sc + bf;
        feat[((size_t)b * T + t) * 128 + co] = o > 0.0f ? o : 0.0f;
    }
}

// --------------------------- reversed-time LSTM -----------------------------
// 1024 threads = (j2 in [0,128)) x (k-eighth q in [0,8)).
// Thread (j2,q): partial dot over k in [16q,16q+16) for gates {j2+128g}.
// Per-thread weights: wh[4][16] f32 (64 VGPR) + wiu[4][8] bf16-packed (32)
// => ~115 VGPRs total, FITS the compiler's 128-VGPR choice (rounds 2-4 showed
// hints cannot raise the budget, so the footprint must shrink instead).
// pad_lds pushes LDS >80KB -> 1 block/CU is a HARD constraint -> backend's
// occupancy target is 4 waves/SIMD = 128-VGPR budget. No spill, no reloads.
__global__ __launch_bounds__(1024)
__attribute__((amdgpu_waves_per_eu(4, 4)))
void k_lstm3(
    const float* __restrict__ feat, const float* __restrict__ w_ih,
    const float* __restrict__ w_hh, const float* __restrict__ b_ih,
    const float* __restrict__ b_hh, float* __restrict__ out, int T)
{
    __shared__ __align__(16) float h_sh[128];
    __shared__ __align__(16) float x_sh[2][128];
    __shared__ float p_sh[32][128];    // [q*4+g][j2], 16 KB
    __shared__ float pad_lds[16384];   // 64 KB occupancy limiter (never written)

    const int b = blockIdx.x;
    const int tid = threadIdx.x;
    const int j2 = tid & 127;
    const int q = tid >> 7;  // 0..7, wave-uniform (waves 2q, 2q+1)

    if (feat == nullptr) pad_lds[tid] = 1.0f;  // keep pad allocated; never true

    // --- load weights into registers ---
    float wh[4][16];        // W_hh[j2+128g][16q+kk], f32 (64 VGPRs)
    unsigned wiu[4][8];     // W_ih same slice, bf16 pairs packed (32 VGPRs)
#pragma unroll
    for (int g = 0; g < 4; ++g) {
        const float* hr = w_hh + (size_t)(j2 + 128 * g) * 128 + 16 * q;
        const float* ir = w_ih + (size_t)(j2 + 128 * g) * 128 + 16 * q;
#pragma unroll
        for (int kk = 0; kk < 16; kk += 4) {
            float4 h4 = *reinterpret_cast<const float4*>(hr + kk);
            wh[g][kk + 0] = h4.x; wh[g][kk + 1] = h4.y;
            wh[g][kk + 2] = h4.z; wh[g][kk + 3] = h4.w;
            float4 i4 = *reinterpret_cast<const float4*>(ir + kk);
            wiu[g][kk / 2]     = (bfr(i4.y) << 16) | bfr(i4.x);
            wiu[g][kk / 2 + 1] = (bfr(i4.w) << 16) | bfr(i4.z);
        }
    }
    float bias[4];  // only consumed by q==0 threads (the pointwise phase)
#pragma unroll
    for (int g = 0; g < 4; ++g)
        bias[g] = b_ih[j2 + 128 * g] + b_hh[j2 + 128 * g];

    // --- init state, stage x for first two steps ---
    float cst = 0.0f;
    if (tid < 128) h_sh[tid] = 0.0f;
    float xnv = 0.0f;
    if (tid < 128) {
        x_sh[0][tid] = feat[((size_t)b * T + (T - 1)) * 128 + tid];
        if (T >= 2) xnv = feat[((size_t)b * T + (T - 2)) * 128 + tid];
    }
    __syncthreads();

    int cur = 0;
    for (int t = T - 1; t >= 0; --t) {
        // ---- phase 1: partial dots (all 1024 threads) ----
        // h/x reads are wave-uniform addresses -> LDS broadcast (conflict-free)
        float acc[4] = {0.0f, 0.0f, 0.0f, 0.0f};
        const float4* hv = reinterpret_cast<const float4*>(h_sh) + 4 * q;
        const float4* xv = reinterpret_cast<const float4*>(x_sh[cur]) + 4 * q;
#pragma unroll
        for (int k4 = 0; k4 < 4; ++k4) {
            float4 h4 = hv[k4];
            float4 x4 = xv[k4];
#pragma unroll
            for (int g = 0; g < 4; ++g) {
                float a = acc[g];
                a += h4.x * wh[g][4 * k4 + 0];
                a += h4.y * wh[g][4 * k4 + 1];
                a += h4.z * wh[g][4 * k4 + 2];
                a += h4.w * wh[g][4 * k4 + 3];
                unsigned u0 = wiu[g][2 * k4], u1 = wiu[g][2 * k4 + 1];
                a += x4.x * __uint_as_float(u0 << 16);
                a += x4.y * __uint_as_float(u0 & 0xffff0000u);
                a += x4.z * __uint_as_float(u1 << 16);
                a += x4.w * __uint_as_float(u1 & 0xffff0000u);
                acc[g] = a;
            }
        }
#pragma unroll
        for (int g = 0; g < 4; ++g)
            p_sh[q * 4 + g][j2] = acc[g];
        __syncthreads();  // A: partials visible

        // ---- phase 2: 8-way reduce + pointwise (threads j<128, q==0) ----
        if (tid < 128) {
            float s[4];
#pragma unroll
            for (int g = 0; g < 4; ++g) {
                float v0 = p_sh[0 * 4 + g][tid] + p_sh[1 * 4 + g][tid];
                float v1 = p_sh[2 * 4 + g][tid] + p_sh[3 * 4 + g][tid];
                float v2 = p_sh[4 * 4 + g][tid] + p_sh[5 * 4 + g][tid];
                float v3 = p_sh[6 * 4 + g][tid] + p_sh[7 * 4 + g][tid];
                s[g] = bias[g] + ((v0 + v1) + (v2 + v3));
            }
            cst = sigf(s[1]) * cst + sigf(s[0]) * tanhfast(s[2]);
            float h = sigf(s[3]) * tanhfast(cst);
            h_sh[tid] = h;
            out[((size_t)b * T + t) * 128 + tid] = h;
            x_sh[cur ^ 1][tid] = xnv;  // x for step t-1
            xnv = (t >= 2) ? feat[((size_t)b * T + (t - 2)) * 128 + tid] : 0.0f;
        }
        cur ^= 1;
        __syncthreads();  // B: h_sh / x_sh ready for next step
    }
}

extern "C" void kernel_launch(void* const* d_in, const int* in_sizes, int n_in,
                              void* d_out, int out_size, void* d_ws, size_t ws_size,
                              hipStream_t stream)
{
    const float* x    = (const float*)d_in[0];
    const float* c1w  = (const float*)d_in[1];
    const float* bn1g = (const float*)d_in[2];
    const float* bn1b = (const float*)d_in[3];
    const float* bn1m = (const float*)d_in[4];
    const float* bn1v = (const float*)d_in[5];
    const float* c2w  = (const float*)d_in[6];
    const float* bn2g = (const float*)d_in[7];
    const float* bn2b = (const float*)d_in[8];
    const float* bn2m = (const float*)d_in[9];
    const float* bn2v = (const float*)d_in[10];
    const float* c3w  = (const float*)d_in[11];
    const float* bn3g = (const float*)d_in[12];
    const float* bn3b = (const float*)d_in[13];
    const float* bn3m = (const float*)d_in[14];
    const float* bn3v = (const float*)d_in[15];
    const float* w_ih = (const float*)d_in[16];
    const float* w_hh = (const float*)d_in[17];
    const float* b_ih = (const float*)d_in[18];
    const float* b_hh = (const float*)d_in[19];
    float* out = (float*)d_out;

    const int B = 64, T = 4096;
    char* ws = (char*)d_ws;
    const size_t sz_y1 = (size_t)B * 32 * T * 4;   // 32 MB
    const size_t sz_y2 = (size_t)B * 64 * T * 4;   // 64 MB

    float* y1   = (float*)ws;
    float* y2   = (float*)(ws + sz_y1);
    float* feat = (float*)(ws + sz_y1 + sz_y2);

    k_conv1<<<dim3(T / 256, B), 256, 0, stream>>>(x, c1w, bn1g, bn1b, bn1m, bn1v, y1, B, T);
    k_conv2<<<dim3(T / 256, B), 256, 0, stream>>>(y1, c2w, bn2g, bn2b, bn2m, bn2v, y2, B, T);
    k_conv3<<<dim3(T / 128, B), 256, 0, stream>>>(y2, c3w, bn3g, bn3b, bn3m, bn3v, feat, B, T);

    k_lstm3<<<dim3(B), 1024, 0, stream>>>(feat, w_ih, w_hh, b_ih, b_hh, out, T);
}

// Round 7
// 10121.127 us; speedup vs baseline: 1.7991x; 1.5303x over previous
//
#include <hip/hip_runtime.h>
#include <cstdint>
#include <cstddef>

#define BN_EPS 1e-5f

typedef __attribute__((ext_vector_type(8))) short  bf16x8;
typedef __attribute__((ext_vector_type(4))) float  f32x4;
typedef __attribute__((ext_vector_type(4))) unsigned u32x4;
typedef __attribute__((ext_vector_type(2))) unsigned u32x2;

__device__ __forceinline__ float sigf(float x) {
    return 1.0f / (1.0f + __expf(-x));
}
__device__ __forceinline__ float tanhfast(float x) {
    return 2.0f / (1.0f + __expf(-2.0f * x)) - 1.0f;
}
__device__ __forceinline__ unsigned bfr(float x) {  // f32 -> bf16 bits (RNE)
    unsigned u = __float_as_uint(x);
    return (u + 0x7fffu + ((u >> 16) & 1u)) >> 16;
}

// ---------------- conv1 + BN + ReLU : x[B,T,9] -> y1[B,32,T] ----------------
__global__ __launch_bounds__(256) void k_conv1(
    const float* __restrict__ x, const float* __restrict__ w,
    const float* __restrict__ g, const float* __restrict__ bb,
    const float* __restrict__ m, const float* __restrict__ v,
    float* __restrict__ y1, int B, int T)
{
    const int TT = 256;
    __shared__ float xs[(TT + 6) * 9];
    const int b = blockIdx.y;
    const int t0 = blockIdx.x * TT;
    const int tid = threadIdx.x;

    for (int idx = tid; idx < (TT + 6) * 9; idx += 256) {
        int row = idx / 9, col = idx - row * 9;
        int tg = t0 - 3 + row;
        xs[idx] = (tg >= 0 && tg < T) ? x[((size_t)b * T + tg) * 9 + col] : 0.0f;
    }
    __syncthreads();

    float xv[63];
#pragma unroll
    for (int k = 0; k < 7; ++k)
#pragma unroll
        for (int ci = 0; ci < 9; ++ci)
            xv[k * 9 + ci] = xs[(tid + k) * 9 + ci];

    const int t = t0 + tid;
    for (int co = 0; co < 32; ++co) {
        float acc = 0.0f;
#pragma unroll
        for (int ci = 0; ci < 9; ++ci)
#pragma unroll
            for (int k = 0; k < 7; ++k)
                acc += xv[k * 9 + ci] * w[(co * 9 + ci) * 7 + k];
        float sc = g[co] / sqrtf(v[co] + BN_EPS);
        float bf = bb[co] - m[co] * sc;
        float o = acc * sc + bf;
        y1[((size_t)b * 32 + co) * T + t] = o > 0.0f ? o : 0.0f;
    }
}

// ---------------- conv2 + BN + ReLU : y1[B,32,T] -> y2[B,64,T] --------------
__global__ __launch_bounds__(256) void k_conv2(
    const float* __restrict__ y1, const float* __restrict__ w,
    const float* __restrict__ g, const float* __restrict__ bb,
    const float* __restrict__ m, const float* __restrict__ v,
    float* __restrict__ y2, int B, int T)
{
    const int TT = 256;
    __shared__ float ys[32 * (TT + 6)];
    const int b = blockIdx.y;
    const int t0 = blockIdx.x * TT;
    const int tid = threadIdx.x;

    for (int idx = tid; idx < 32 * (TT + 6); idx += 256) {
        int ci = idx / (TT + 6), i = idx - ci * (TT + 6);
        int tg = t0 - 3 + i;
        ys[idx] = (tg >= 0 && tg < T) ? y1[((size_t)b * 32 + ci) * T + tg] : 0.0f;
    }
    __syncthreads();

    float acc[64];
#pragma unroll
    for (int co = 0; co < 64; ++co) acc[co] = 0.0f;

    for (int ci = 0; ci < 32; ++ci) {
        float yw[7];
#pragma unroll
        for (int k = 0; k < 7; ++k) yw[k] = ys[ci * (TT + 6) + tid + k];
#pragma unroll
        for (int co = 0; co < 64; ++co)
#pragma unroll
            for (int k = 0; k < 7; ++k)
                acc[co] += yw[k] * w[(co * 32 + ci) * 7 + k];
    }

    const int t = t0 + tid;
    for (int co = 0; co < 64; ++co) {
        float sc = g[co] / sqrtf(v[co] + BN_EPS);
        float bf = bb[co] - m[co] * sc;
        float o = acc[co] * sc + bf;
        y2[((size_t)b * 64 + co) * T + t] = o > 0.0f ? o : 0.0f;
    }
}

// ------------- conv3 + BN + ReLU : y2[B,64,T] -> feat[B,T,128] --------------
__global__ __launch_bounds__(256) void k_conv3(
    const float* __restrict__ y2, const float* __restrict__ w,
    const float* __restrict__ g, const float* __restrict__ bb,
    const float* __restrict__ m, const float* __restrict__ v,
    float* __restrict__ feat, int B, int T)
{
    const int TT = 128;
    __shared__ float ys[64 * (TT + 6)];
    const int b = blockIdx.y;
    const int t0 = blockIdx.x * TT;
    const int tid = threadIdx.x;
    const int tl = tid & 127;
    const int half = __builtin_amdgcn_readfirstlane(tid >> 7);  // wave-uniform

    for (int idx = tid; idx < 64 * (TT + 6); idx += 256) {
        int ci = idx / (TT + 6), i = idx - ci * (TT + 6);
        int tg = t0 - 3 + i;
        ys[idx] = (tg >= 0 && tg < T) ? y2[((size_t)b * 64 + ci) * T + tg] : 0.0f;
    }
    __syncthreads();

    float acc[64];
#pragma unroll
    for (int q = 0; q < 64; ++q) acc[q] = 0.0f;

    for (int ci = 0; ci < 64; ++ci) {
        float yw[7];
#pragma unroll
        for (int k = 0; k < 7; ++k) yw[k] = ys[ci * (TT + 6) + tl + k];
#pragma unroll
        for (int q = 0; q < 64; ++q)
#pragma unroll
            for (int k = 0; k < 7; ++k)
                acc[q] += yw[k] * w[((half * 64 + q) * 64 + ci) * 7 + k];
    }

    const int t = t0 + tl;
    for (int q = 0; q < 64; ++q) {
        int co = half * 64 + q;
        float sc = g[co] / sqrtf(v[co] + BN_EPS);
        float bf = bb[co] - m[co] * sc;
        float o = acc[q] * sc + bf;
        feat[((size_t)b * T + t) * 128 + co] = o > 0.0f ? o : 0.0f;
    }
}

// --------------------------- reversed-time LSTM (MFMA) ----------------------
// 4 blocks x 16 batches. 1024 threads = 16 waves; wave wv owns gate rows
// [wv*32, wv*32+32) for ALL 16 batches (MFMA N=16 cols = batches).
// Combined weights W'[512][256] = interleave(W_hh, W_ih) along k
// (k'=2j -> W_hh[.,j], k'=2j+1 -> W_ih[.,j]) live in A-fragments: 64 VGPR.
// hx[batch][j] u32 = (bf16 h[j] | bf16 x[j]<<16), XOR-swizzled for the
// B-fragment ds_read_b128s. Gate outputs go through XOR-swizzled g2.
// LDS is padded to ~81 KB (pad kept alive by runtime `T==0` guard) ->
// 1 block/CU hard -> VGPR budget 128; demand ~110 -> no spill.
// R6 bug (NaN): tile-1 D write used row offset +64 instead of +16 -> gate
// rows 16..31 of each band never written -> uninit LDS reads. Fixed here.
#define SWZ(b) (((b) & 7) << 4)

__global__ __launch_bounds__(1024) void k_lstm_mfma(
    const float* __restrict__ feat, const float* __restrict__ w_ih,
    const float* __restrict__ w_hh, const float* __restrict__ b_ih,
    const float* __restrict__ b_hh, float* __restrict__ out, int T)
{
    __shared__ __align__(16) unsigned hx[2][16][128];  // 16 KB, swizzled
    __shared__ __align__(16) float g2[16][512];        // 32 KB, swizzled
    __shared__ float pad_lds[8448];                    // 33 KB occupancy forcer

    const int tid  = threadIdx.x;
    const int bk   = blockIdx.x;          // batches [bk*16, bk*16+16)
    if (T == 0) pad_lds[tid] = 1.0f;      // runtime-unprovable -> pad survives

    const int wv    = tid >> 6;           // wave 0..15
    const int lane  = tid & 63;
    const int batch = lane & 15;          // MFMA col / row-in-tile
    const int kg    = lane >> 4;          // 0..3 k-group

    // pointwise role: wave wv handles batch pb = wv, lanes cover j pairs
    const int pb = wv;
    const int pj = (lane) * 2;            // j in {0,2,...,126}
    const size_t gbase = ((size_t)(bk * 16 + pb)) * T;

    // ---- load A-fragments: W'[wv*32 + t2*16 + (lane&15)][ks*32+kg*8 .. +8) ----
    bf16x8 afr[2][8];
#pragma unroll
    for (int t2 = 0; t2 < 2; ++t2) {
        const int row = wv * 32 + t2 * 16 + batch;
#pragma unroll
        for (int ks = 0; ks < 8; ++ks) {
            const int j0 = ks * 16 + kg * 4;  // (ks*32 + kg*8) / 2
            float4 h4 = *reinterpret_cast<const float4*>(w_hh + (size_t)row * 128 + j0);
            float4 i4 = *reinterpret_cast<const float4*>(w_ih + (size_t)row * 128 + j0);
            u32x4 u;
            u.x = (bfr(i4.x) << 16) | bfr(h4.x);
            u.y = (bfr(i4.y) << 16) | bfr(h4.y);
            u.z = (bfr(i4.z) << 16) | bfr(h4.z);
            u.w = (bfr(i4.w) << 16) | bfr(h4.w);
            afr[t2][ks] = __builtin_bit_cast(bf16x8, u);
        }
    }

    float bias[4][2];
#pragma unroll
    for (int g = 0; g < 4; ++g) {
        bias[g][0] = b_ih[pj + 128 * g] + b_hh[pj + 128 * g];
        bias[g][1] = b_ih[pj + 1 + 128 * g] + b_hh[pj + 1 + 128 * g];
    }
    float cst[2] = {0.0f, 0.0f};

    // ---- init hx[0]: h=0, x = feat[T-1] ----
    {
        float2 x0 = *reinterpret_cast<const float2*>(feat + (gbase + (T - 1)) * 128 + pj);
        u32x2 u;
        u.x = bfr(x0.x) << 16;  // h=0 in low half
        u.y = bfr(x0.y) << 16;
        *reinterpret_cast<u32x2*>(
            (char*)&hx[0][pb][0] + ((pj * 4) ^ SWZ(pb))) = u;
    }
    __syncthreads();

    int cur = 0;
    for (int t = T - 1; t >= 0; --t) {
        // ---- phase A: prefetch x(t-1); B-frag reads + MFMA; write g2 ----
        const int tp = (t > 0) ? t - 1 : 0;
        float2 xp = *reinterpret_cast<const float2*>(feat + (gbase + tp) * 128 + pj);

        f32x4 acc0 = {0.f, 0.f, 0.f, 0.f};
        f32x4 acc1 = {0.f, 0.f, 0.f, 0.f};
        const char* hrow = (const char*)&hx[cur][batch][0];
#pragma unroll
        for (int half = 0; half < 2; ++half) {
            u32x4 bq[4];
#pragma unroll
            for (int s = 0; s < 4; ++s) {
                const int ks = half * 4 + s;
                bq[s] = *reinterpret_cast<const u32x4*>(
                    hrow + ((ks * 64 + kg * 16) ^ SWZ(batch)));
            }
#pragma unroll
            for (int s = 0; s < 4; ++s) {
                const int ks = half * 4 + s;
                bf16x8 bf = __builtin_bit_cast(bf16x8, bq[s]);
                acc0 = __builtin_amdgcn_mfma_f32_16x16x32_bf16(afr[0][ks], bf, acc0, 0, 0, 0);
                acc1 = __builtin_amdgcn_mfma_f32_16x16x32_bf16(afr[1][ks], bf, acc1, 0, 0, 0);
            }
        }
        // D layout: col=lane&15(=batch), row-in-tile = kg*4 + reg  (m89 mapping)
        // tile 0 -> gate rows wv*32 + kg*4 + reg; tile 1 -> +16 rows.
        {
            char* grow = (char*)&g2[batch][0];
            const int r0 = (wv * 32 + kg * 4) * 4;
            *reinterpret_cast<f32x4*>(grow + (r0 ^ SWZ(batch))) = acc0;
            const int r1 = (wv * 32 + 16 + kg * 4) * 4;   // FIXED: +16, not +64
            *reinterpret_cast<f32x4*>(grow + (r1 ^ SWZ(batch))) = acc1;
        }
        __syncthreads();  // A: gates visible

        // ---- phase B: pointwise for (pb, pj) and (pb, pj+1) ----
        {
            const char* grow = (const char*)&g2[pb][0];
            float2 gv[4];
#pragma unroll
            for (int g = 0; g < 4; ++g)
                gv[g] = *reinterpret_cast<const float2*>(
                    grow + (((pj + 128 * g) * 4) ^ SWZ(pb)));

            float h0, h1;
            {
                float gi = sigf(gv[0].x + bias[0][0]);
                float gf = sigf(gv[1].x + bias[1][0]);
                float gg = tanhfast(gv[2].x + bias[2][0]);
                float go = sigf(gv[3].x + bias[3][0]);
                cst[0] = gf * cst[0] + gi * gg;
                h0 = go * tanhfast(cst[0]);
            }
            {
                float gi = sigf(gv[0].y + bias[0][1]);
                float gf = sigf(gv[1].y + bias[1][1]);
                float gg = tanhfast(gv[2].y + bias[2][1]);
                float go = sigf(gv[3].y + bias[3][1]);
                cst[1] = gf * cst[1] + gi * gg;
                h1 = go * tanhfast(cst[1]);
            }
            *reinterpret_cast<float2*>(out + (gbase + t) * 128 + pj) =
                make_float2(h0, h1);
            u32x2 u;
            u.x = (bfr(xp.x) << 16) | bfr(h0);
            u.y = (bfr(xp.y) << 16) | bfr(h1);
            *reinterpret_cast<u32x2*>(
                (char*)&hx[cur ^ 1][pb][0] + ((pj * 4) ^ SWZ(pb))) = u;
        }
        cur ^= 1;
        __syncthreads();  // B: hx ready for next step
    }
}

extern "C" void kernel_launch(void* const* d_in, const int* in_sizes, int n_in,
                              void* d_out, int out_size, void* d_ws, size_t ws_size,
                              hipStream_t stream)
{
    const float* x    = (const float*)d_in[0];
    const float* c1w  = (const float*)d_in[1];
    const float* bn1g = (const float*)d_in[2];
    const float* bn1b = (const float*)d_in[3];
    const float* bn1m = (const float*)d_in[4];
    const float* bn1v = (const float*)d_in[5];
    const float* c2w  = (const float*)d_in[6];
    const float* bn2g = (const float*)d_in[7];
    const float* bn2b = (const float*)d_in[8];
    const float* bn2m = (const float*)d_in[9];
    const float* bn2v = (const float*)d_in[10];
    const float* c3w  = (const float*)d_in[11];
    const float* bn3g = (const float*)d_in[12];
    const float* bn3b = (const float*)d_in[13];
    const float* bn3m = (const float*)d_in[14];
    const float* bn3v = (const float*)d_in[15];
    const float* w_ih = (const float*)d_in[16];
    const float* w_hh = (const float*)d_in[17];
    const float* b_ih = (const float*)d_in[18];
    const float* b_hh = (const float*)d_in[19];
    float* out = (float*)d_out;

    const int B = 64, T = 4096;
    char* ws = (char*)d_ws;
    const size_t sz_y1 = (size_t)B * 32 * T * 4;   // 32 MB
    const size_t sz_y2 = (size_t)B * 64 * T * 4;   // 64 MB

    float* y1   = (float*)ws;
    float* y2   = (float*)(ws + sz_y1);
    float* feat = (float*)(ws + sz_y1 + sz_y2);

    k_conv1<<<dim3(T / 256, B), 256, 0, stream>>>(x, c1w, bn1g, bn1b, bn1m, bn1v, y1, B, T);
    k_conv2<<<dim3(T / 256, B), 256, 0, stream>>>(y1, c2w, bn2g, bn2b, bn2m, bn2v, y2, B, T);
    k_conv3<<<dim3(T / 128, B), 256, 0, stream>>>(y2, c3w, bn3g, bn3b, bn3m, bn3v, feat, B, T);

    k_lstm_mfma<<<dim3(4), 1024, 0, stream>>>(feat, w_ih, w_hh, b_ih, b_hh, out, T);
}

// Round 8
// 10113.164 us; speedup vs baseline: 1.8006x; 1.0008x over previous
//
#include <hip/hip_runtime.h>
#include <cstdint>
#include <cstddef>

#define BN_EPS 1e-5f

typedef __attribute__((ext_vector_type(8))) short  bf16x8;
typedef __attribute__((ext_vector_type(4))) float  f32x4;
typedef __attribute__((ext_vector_type(4))) unsigned u32x4;
typedef __attribute__((ext_vector_type(2))) unsigned u32x2;

__device__ __forceinline__ float sigf(float x) {
    return 1.0f / (1.0f + __expf(-x));
}
__device__ __forceinline__ float tanhfast(float x) {
    return 2.0f / (1.0f + __expf(-2.0f * x)) - 1.0f;
}
__device__ __forceinline__ unsigned bfr(float x) {  // f32 -> bf16 bits (RNE)
    unsigned u = __float_as_uint(x);
    return (u + 0x7fffu + ((u >> 16) & 1u)) >> 16;
}

// ---------------- conv1 + BN + ReLU : x[B,T,9] -> y1[B,32,T] ----------------
__global__ __launch_bounds__(256) void k_conv1(
    const float* __restrict__ x, const float* __restrict__ w,
    const float* __restrict__ g, const float* __restrict__ bb,
    const float* __restrict__ m, const float* __restrict__ v,
    float* __restrict__ y1, int B, int T)
{
    const int TT = 256;
    __shared__ float xs[(TT + 6) * 9];
    const int b = blockIdx.y;
    const int t0 = blockIdx.x * TT;
    const int tid = threadIdx.x;

    for (int idx = tid; idx < (TT + 6) * 9; idx += 256) {
        int row = idx / 9, col = idx - row * 9;
        int tg = t0 - 3 + row;
        xs[idx] = (tg >= 0 && tg < T) ? x[((size_t)b * T + tg) * 9 + col] : 0.0f;
    }
    __syncthreads();

    float xv[63];
#pragma unroll
    for (int k = 0; k < 7; ++k)
#pragma unroll
        for (int ci = 0; ci < 9; ++ci)
            xv[k * 9 + ci] = xs[(tid + k) * 9 + ci];

    const int t = t0 + tid;
    for (int co = 0; co < 32; ++co) {
        float acc = 0.0f;
#pragma unroll
        for (int ci = 0; ci < 9; ++ci)
#pragma unroll
            for (int k = 0; k < 7; ++k)
                acc += xv[k * 9 + ci] * w[(co * 9 + ci) * 7 + k];
        float sc = g[co] / sqrtf(v[co] + BN_EPS);
        float bf = bb[co] - m[co] * sc;
        float o = acc * sc + bf;
        y1[((size_t)b * 32 + co) * T + t] = o > 0.0f ? o : 0.0f;
    }
}

// ---------------- conv2 + BN + ReLU : y1[B,32,T] -> y2[B,64,T] --------------
__global__ __launch_bounds__(256) void k_conv2(
    const float* __restrict__ y1, const float* __restrict__ w,
    const float* __restrict__ g, const float* __restrict__ bb,
    const float* __restrict__ m, const float* __restrict__ v,
    float* __restrict__ y2, int B, int T)
{
    const int TT = 256;
    __shared__ float ys[32 * (TT + 6)];
    const int b = blockIdx.y;
    const int t0 = blockIdx.x * TT;
    const int tid = threadIdx.x;

    for (int idx = tid; idx < 32 * (TT + 6); idx += 256) {
        int ci = idx / (TT + 6), i = idx - ci * (TT + 6);
        int tg = t0 - 3 + i;
        ys[idx] = (tg >= 0 && tg < T) ? y1[((size_t)b * 32 + ci) * T + tg] : 0.0f;
    }
    __syncthreads();

    float acc[64];
#pragma unroll
    for (int co = 0; co < 64; ++co) acc[co] = 0.0f;

    for (int ci = 0; ci < 32; ++ci) {
        float yw[7];
#pragma unroll
        for (int k = 0; k < 7; ++k) yw[k] = ys[ci * (TT + 6) + tid + k];
#pragma unroll
        for (int co = 0; co < 64; ++co)
#pragma unroll
            for (int k = 0; k < 7; ++k)
                acc[co] += yw[k] * w[(co * 32 + ci) * 7 + k];
    }

    const int t = t0 + tid;
    for (int co = 0; co < 64; ++co) {
        float sc = g[co] / sqrtf(v[co] + BN_EPS);
        float bf = bb[co] - m[co] * sc;
        float o = acc[co] * sc + bf;
        y2[((size_t)b * 64 + co) * T + t] = o > 0.0f ? o : 0.0f;
    }
}

// ------------- conv3 + BN + ReLU : y2[B,64,T] -> feat[B,T,128] --------------
__global__ __launch_bounds__(256) void k_conv3(
    const float* __restrict__ y2, const float* __restrict__ w,
    const float* __restrict__ g, const float* __restrict__ bb,
    const float* __restrict__ m, const float* __restrict__ v,
    float* __restrict__ feat, int B, int T)
{
    const int TT = 128;
    __shared__ float ys[64 * (TT + 6)];
    const int b = blockIdx.y;
    const int t0 = blockIdx.x * TT;
    const int tid = threadIdx.x;
    const int tl = tid & 127;
    const int half = __builtin_amdgcn_readfirstlane(tid >> 7);  // wave-uniform

    for (int idx = tid; idx < 64 * (TT + 6); idx += 256) {
        int ci = idx / (TT + 6), i = idx - ci * (TT + 6);
        int tg = t0 - 3 + i;
        ys[idx] = (tg >= 0 && tg < T) ? y2[((size_t)b * 64 + ci) * T + tg] : 0.0f;
    }
    __syncthreads();

    float acc[64];
#pragma unroll
    for (int q = 0; q < 64; ++q) acc[q] = 0.0f;

    for (int ci = 0; ci < 64; ++ci) {
        float yw[7];
#pragma unroll
        for (int k = 0; k < 7; ++k) yw[k] = ys[ci * (TT + 6) + tl + k];
#pragma unroll
        for (int q = 0; q < 64; ++q)
#pragma unroll
            for (int k = 0; k < 7; ++k)
                acc[q] += yw[k] * w[((half * 64 + q) * 64 + ci) * 7 + k];
    }

    const int t = t0 + tl;
    for (int q = 0; q < 64; ++q) {
        int co = half * 64 + q;
        float sc = g[co] / sqrtf(v[co] + BN_EPS);
        float bf = bb[co] - m[co] * sc;
        float o = acc[q] * sc + bf;
        feat[((size_t)b * T + t) * 128 + co] = o > 0.0f ? o : 0.0f;
    }
}

// --------------------------- reversed-time LSTM (MFMA) ----------------------
// 4 blocks x 16 batches. 1024 threads = 16 waves; wave wv owns gate rows
// [wv*32, wv*32+32) for ALL 16 batches (MFMA N=16 cols = batches).
// Combined weights W'[512][256] = interleave(W_hh, W_ih) along k live in
// A-fragments (64 VGPR). hx packs (bf16 h | bf16 x<<16), XOR-swizzled.
// OCCUPANCY FORCING (R7 lesson): a write-only LDS pad gets dead-store-
// eliminated -> 48KB LDS -> 2 blocks/CU -> 64-VGPR budget -> afr spills to
// scratch, reloaded every step (8.4ms). The pad must be READ into a global
// store inside the uniformly-false `T==0` branch so DCE cannot remove the
// allocation. 81KB LDS -> 1 block/CU -> 128-VGPR budget; demand ~110 -> fits.
#define SWZ(b) (((b) & 7) << 4)

__global__ __launch_bounds__(1024) void k_lstm_mfma(
    const float* __restrict__ feat, const float* __restrict__ w_ih,
    const float* __restrict__ w_hh, const float* __restrict__ b_ih,
    const float* __restrict__ b_hh, float* __restrict__ out, int T)
{
    __shared__ __align__(16) unsigned hx[2][16][128];  // 16 KB, swizzled
    __shared__ __align__(16) float g2[16][512];        // 32 KB, swizzled
    __shared__ float pad_lds[8448];                    // 33 KB occupancy forcer

    const int tid  = threadIdx.x;
    const int bk   = blockIdx.x;          // batches [bk*16, bk*16+16)

    // Occupancy forcer that survives DCE: store -> barrier -> load -> global
    // store, all inside a block-uniform branch that is false at runtime
    // (T==4096). The load feeding a global store pins the allocation.
    if (T == 0) {
        pad_lds[tid] = b_ih[tid & 511];
        __syncthreads();
        out[tid] = pad_lds[(tid * 131 + 7) & 8191];
    }

    const int wv    = tid >> 6;           // wave 0..15
    const int lane  = tid & 63;
    const int batch = lane & 15;          // MFMA col / row-in-tile
    const int kg    = lane >> 4;          // 0..3 k-group

    // pointwise role: wave wv handles batch pb = wv, lanes cover j pairs
    const int pb = wv;
    const int pj = (lane) * 2;            // j in {0,2,...,126}
    const size_t gbase = ((size_t)(bk * 16 + pb)) * T;

    // ---- load A-fragments: W'[wv*32 + t2*16 + (lane&15)][ks*32+kg*8 .. +8) ----
    bf16x8 afr[2][8];
#pragma unroll
    for (int t2 = 0; t2 < 2; ++t2) {
        const int row = wv * 32 + t2 * 16 + batch;
#pragma unroll
        for (int ks = 0; ks < 8; ++ks) {
            const int j0 = ks * 16 + kg * 4;  // (ks*32 + kg*8) / 2
            float4 h4 = *reinterpret_cast<const float4*>(w_hh + (size_t)row * 128 + j0);
            float4 i4 = *reinterpret_cast<const float4*>(w_ih + (size_t)row * 128 + j0);
            u32x4 u;
            u.x = (bfr(i4.x) << 16) | bfr(h4.x);
            u.y = (bfr(i4.y) << 16) | bfr(h4.y);
            u.z = (bfr(i4.z) << 16) | bfr(h4.z);
            u.w = (bfr(i4.w) << 16) | bfr(h4.w);
            afr[t2][ks] = __builtin_bit_cast(bf16x8, u);
        }
    }

    float bias[4][2];
#pragma unroll
    for (int g = 0; g < 4; ++g) {
        bias[g][0] = b_ih[pj + 128 * g] + b_hh[pj + 128 * g];
        bias[g][1] = b_ih[pj + 1 + 128 * g] + b_hh[pj + 1 + 128 * g];
    }
    float cst[2] = {0.0f, 0.0f};

    // ---- init hx[0]: h=0, x = feat[T-1] ----
    {
        float2 x0 = *reinterpret_cast<const float2*>(feat + (gbase + (T - 1)) * 128 + pj);
        u32x2 u;
        u.x = bfr(x0.x) << 16;  // h=0 in low half
        u.y = bfr(x0.y) << 16;
        *reinterpret_cast<u32x2*>(
            (char*)&hx[0][pb][0] + ((pj * 4) ^ SWZ(pb))) = u;
    }
    __syncthreads();

    int cur = 0;
    for (int t = T - 1; t >= 0; --t) {
        // ---- phase A: prefetch x(t-1); B-frag reads + MFMA; write g2 ----
        const int tp = (t > 0) ? t - 1 : 0;
        float2 xp = *reinterpret_cast<const float2*>(feat + (gbase + tp) * 128 + pj);

        f32x4 acc0 = {0.f, 0.f, 0.f, 0.f};
        f32x4 acc1 = {0.f, 0.f, 0.f, 0.f};
        const char* hrow = (const char*)&hx[cur][batch][0];
#pragma unroll
        for (int half = 0; half < 2; ++half) {
            u32x4 bq[4];
#pragma unroll
            for (int s = 0; s < 4; ++s) {
                const int ks = half * 4 + s;
                bq[s] = *reinterpret_cast<const u32x4*>(
                    hrow + ((ks * 64 + kg * 16) ^ SWZ(batch)));
            }
#pragma unroll
            for (int s = 0; s < 4; ++s) {
                const int ks = half * 4 + s;
                bf16x8 bf = __builtin_bit_cast(bf16x8, bq[s]);
                acc0 = __builtin_amdgcn_mfma_f32_16x16x32_bf16(afr[0][ks], bf, acc0, 0, 0, 0);
                acc1 = __builtin_amdgcn_mfma_f32_16x16x32_bf16(afr[1][ks], bf, acc1, 0, 0, 0);
            }
        }
        // D layout: col=lane&15(=batch), row-in-tile = kg*4 + reg  (m89 mapping)
        // tile 0 -> gate rows wv*32 + kg*4 + reg; tile 1 -> +16 rows.
        {
            char* grow = (char*)&g2[batch][0];
            const int r0 = (wv * 32 + kg * 4) * 4;
            *reinterpret_cast<f32x4*>(grow + (r0 ^ SWZ(batch))) = acc0;
            const int r1 = (wv * 32 + 16 + kg * 4) * 4;
            *reinterpret_cast<f32x4*>(grow + (r1 ^ SWZ(batch))) = acc1;
        }
        __syncthreads();  // A: gates visible

        // ---- phase B: pointwise for (pb, pj) and (pb, pj+1) ----
        {
            const char* grow = (const char*)&g2[pb][0];
            float2 gv[4];
#pragma unroll
            for (int g = 0; g < 4; ++g)
                gv[g] = *reinterpret_cast<const float2*>(
                    grow + (((pj + 128 * g) * 4) ^ SWZ(pb)));

            float h0, h1;
            {
                float gi = sigf(gv[0].x + bias[0][0]);
                float gf = sigf(gv[1].x + bias[1][0]);
                float gg = tanhfast(gv[2].x + bias[2][0]);
                float go = sigf(gv[3].x + bias[3][0]);
                cst[0] = gf * cst[0] + gi * gg;
                h0 = go * tanhfast(cst[0]);
            }
            {
                float gi = sigf(gv[0].y + bias[0][1]);
                float gf = sigf(gv[1].y + bias[1][1]);
                float gg = tanhfast(gv[2].y + bias[2][1]);
                float go = sigf(gv[3].y + bias[3][1]);
                cst[1] = gf * cst[1] + gi * gg;
                h1 = go * tanhfast(cst[1]);
            }
            *reinterpret_cast<float2*>(out + (gbase + t) * 128 + pj) =
                make_float2(h0, h1);
            u32x2 u;
            u.x = (bfr(xp.x) << 16) | bfr(h0);
            u.y = (bfr(xp.y) << 16) | bfr(h1);
            *reinterpret_cast<u32x2*>(
                (char*)&hx[cur ^ 1][pb][0] + ((pj * 4) ^ SWZ(pb))) = u;
        }
        cur ^= 1;
        __syncthreads();  // B: hx ready for next step
    }
}

extern "C" void kernel_launch(void* const* d_in, const int* in_sizes, int n_in,
                              void* d_out, int out_size, void* d_ws, size_t ws_size,
                              hipStream_t stream)
{
    const float* x    = (const float*)d_in[0];
    const float* c1w  = (const float*)d_in[1];
    const float* bn1g = (const float*)d_in[2];
    const float* bn1b = (const float*)d_in[3];
    const float* bn1m = (const float*)d_in[4];
    const float* bn1v = (const float*)d_in[5];
    const float* c2w  = (const float*)d_in[6];
    const float* bn2g = (const float*)d_in[7];
    const float* bn2b = (const float*)d_in[8];
    const float* bn2m = (const float*)d_in[9];
    const float* bn2v = (const float*)d_in[10];
    const float* c3w  = (const float*)d_in[11];
    const float* bn3g = (const float*)d_in[12];
    const float* bn3b = (const float*)d_in[13];
    const float* bn3m = (const float*)d_in[14];
    const float* bn3v = (const float*)d_in[15];
    const float* w_ih = (const float*)d_in[16];
    const float* w_hh = (const float*)d_in[17];
    const float* b_ih = (const float*)d_in[18];
    const float* b_hh = (const float*)d_in[19];
    float* out = (float*)d_out;

    const int B = 64, T = 4096;
    char* ws = (char*)d_ws;
    const size_t sz_y1 = (size_t)B * 32 * T * 4;   // 32 MB
    const size_t sz_y2 = (size_t)B * 64 * T * 4;   // 64 MB

    float* y1   = (float*)ws;
    float* y2   = (float*)(ws + sz_y1);
    float* feat = (float*)(ws + sz_y1 + sz_y2);

    k_conv1<<<dim3(T / 256, B), 256, 0, stream>>>(x, c1w, bn1g, bn1b, bn1m, bn1v, y1, B, T);
    k_conv2<<<dim3(T / 256, B), 256, 0, stream>>>(y1, c2w, bn2g, bn2b, bn2m, bn2v, y2, B, T);
    k_conv3<<<dim3(T / 128, B), 256, 0, stream>>>(y2, c3w, bn3g, bn3b, bn3m, bn3v, feat, B, T);

    k_lstm_mfma<<<dim3(4), 1024, 0, stream>>>(feat, w_ih, w_hh, b_ih, b_hh, out, T);
}

// Round 9
// 9277.932 us; speedup vs baseline: 1.9626x; 1.0900x over previous
//
#include <hip/hip_runtime.h>
#include <cstdint>
#include <cstddef>

#define BN_EPS 1e-5f

typedef __attribute__((ext_vector_type(8))) short  bf16x8;
typedef __attribute__((ext_vector_type(4))) float  f32x4;
typedef __attribute__((ext_vector_type(4))) unsigned u32x4;

__device__ __forceinline__ float sigf(float x) {
    return 1.0f / (1.0f + __expf(-x));
}
__device__ __forceinline__ float tanhfast(float x) {
    return 2.0f / (1.0f + __expf(-2.0f * x)) - 1.0f;
}
__device__ __forceinline__ unsigned bfr(float x) {  // f32 -> bf16 bits (RNE)
    unsigned u = __float_as_uint(x);
    return (u + 0x7fffu + ((u >> 16) & 1u)) >> 16;
}

// ---------------- conv1 + BN + ReLU : x[B,T,9] -> y1[B,32,T] ----------------
__global__ __launch_bounds__(256) void k_conv1(
    const float* __restrict__ x, const float* __restrict__ w,
    const float* __restrict__ g, const float* __restrict__ bb,
    const float* __restrict__ m, const float* __restrict__ v,
    float* __restrict__ y1, int B, int T)
{
    const int TT = 256;
    __shared__ float xs[(TT + 6) * 9];
    const int b = blockIdx.y;
    const int t0 = blockIdx.x * TT;
    const int tid = threadIdx.x;

    for (int idx = tid; idx < (TT + 6) * 9; idx += 256) {
        int row = idx / 9, col = idx - row * 9;
        int tg = t0 - 3 + row;
        xs[idx] = (tg >= 0 && tg < T) ? x[((size_t)b * T + tg) * 9 + col] : 0.0f;
    }
    __syncthreads();

    float xv[63];
#pragma unroll
    for (int k = 0; k < 7; ++k)
#pragma unroll
        for (int ci = 0; ci < 9; ++ci)
            xv[k * 9 + ci] = xs[(tid + k) * 9 + ci];

    const int t = t0 + tid;
    for (int co = 0; co < 32; ++co) {
        float acc = 0.0f;
#pragma unroll
        for (int ci = 0; ci < 9; ++ci)
#pragma unroll
            for (int k = 0; k < 7; ++k)
                acc += xv[k * 9 + ci] * w[(co * 9 + ci) * 7 + k];
        float sc = g[co] / sqrtf(v[co] + BN_EPS);
        float bf = bb[co] - m[co] * sc;
        float o = acc * sc + bf;
        y1[((size_t)b * 32 + co) * T + t] = o > 0.0f ? o : 0.0f;
    }
}

// ---------------- conv2 + BN + ReLU : y1[B,32,T] -> y2[B,64,T] --------------
__global__ __launch_bounds__(256) void k_conv2(
    const float* __restrict__ y1, const float* __restrict__ w,
    const float* __restrict__ g, const float* __restrict__ bb,
    const float* __restrict__ m, const float* __restrict__ v,
    float* __restrict__ y2, int B, int T)
{
    const int TT = 256;
    __shared__ float ys[32 * (TT + 6)];
    const int b = blockIdx.y;
    const int t0 = blockIdx.x * TT;
    const int tid = threadIdx.x;

    for (int idx = tid; idx < 32 * (TT + 6); idx += 256) {
        int ci = idx / (TT + 6), i = idx - ci * (TT + 6);
        int tg = t0 - 3 + i;
        ys[idx] = (tg >= 0 && tg < T) ? y1[((size_t)b * 32 + ci) * T + tg] : 0.0f;
    }
    __syncthreads();

    float acc[64];
#pragma unroll
    for (int co = 0; co < 64; ++co) acc[co] = 0.0f;

    for (int ci = 0; ci < 32; ++ci) {
        float yw[7];
#pragma unroll
        for (int k = 0; k < 7; ++k) yw[k] = ys[ci * (TT + 6) + tid + k];
#pragma unroll
        for (int co = 0; co < 64; ++co)
#pragma unroll
            for (int k = 0; k < 7; ++k)
                acc[co] += yw[k] * w[(co * 32 + ci) * 7 + k];
    }

    const int t = t0 + tid;
    for (int co = 0; co < 64; ++co) {
        float sc = g[co] / sqrtf(v[co] + BN_EPS);
        float bf = bb[co] - m[co] * sc;
        float o = acc[co] * sc + bf;
        y2[((size_t)b * 64 + co) * T + t] = o > 0.0f ? o : 0.0f;
    }
}

// ------------- conv3 + BN + ReLU : y2[B,64,T] -> feat[B,T,128] --------------
__global__ __launch_bounds__(256) void k_conv3(
    const float* __restrict__ y2, const float* __restrict__ w,
    const float* __restrict__ g, const float* __restrict__ bb,
    const float* __restrict__ m, const float* __restrict__ v,
    float* __restrict__ feat, int B, int T)
{
    const int TT = 128;
    __shared__ float ys[64 * (TT + 6)];
    const int b = blockIdx.y;
    const int t0 = blockIdx.x * TT;
    const int tid = threadIdx.x;
    const int tl = tid & 127;
    const int half = __builtin_amdgcn_readfirstlane(tid >> 7);  // wave-uniform

    for (int idx = tid; idx < 64 * (TT + 6); idx += 256) {
        int ci = idx / (TT + 6), i = idx - ci * (TT + 6);
        int tg = t0 - 3 + i;
        ys[idx] = (tg >= 0 && tg < T) ? y2[((size_t)b * 64 + ci) * T + tg] : 0.0f;
    }
    __syncthreads();

    float acc[64];
#pragma unroll
    for (int q = 0; q < 64; ++q) acc[q] = 0.0f;

    for (int ci = 0; ci < 64; ++ci) {
        float yw[7];
#pragma unroll
        for (int k = 0; k < 7; ++k) yw[k] = ys[ci * (TT + 6) + tl + k];
#pragma unroll
        for (int q = 0; q < 64; ++q)
#pragma unroll
            for (int k = 0; k < 7; ++k)
                acc[q] += yw[k] * w[((half * 64 + q) * 64 + ci) * 7 + k];
    }

    const int t = t0 + tl;
    for (int q = 0; q < 64; ++q) {
        int co = half * 64 + q;
        float sc = g[co] / sqrtf(v[co] + BN_EPS);
        float bf = bb[co] - m[co] * sc;
        float o = acc[q] * sc + bf;
        feat[((size_t)b * T + t) * 128 + co] = o > 0.0f ? o : 0.0f;
    }
}

// --------------------------- reversed-time LSTM (MFMA v2) -------------------
// 512 threads = 8 waves, 16 batches/block, 4 blocks. Wave wv owns UNITS
// [wv*16, wv*16+16); its 4 MFMA row-tiles are the 4 GATES of those units
// (tile g rows = units). D-frag: lane (c=lane&15, q=lane>>4) holds gate-g
// pre-activation for batch c, units wv*16+4q+{0..3} -> all 4 gates land in
// the SAME lane -> pointwise is in-lane: no gate LDS buffer, no 2nd barrier.
// Weights (k' = interleave(W_hh,W_ih), K'=256): gates 0,1 A-frags in VGPRs
// (64 regs; 512-thr blocks get a 128-reg budget per R2-R8 observations),
// gates 2,3 in LDS in exact fragment order (lane-stride-1 ds_read_b128,
// conflict-free). LDS = 128K wlds + 16K hx = 144KB -> 1 block/CU naturally.
#define SWZ(b) (((b) & 7) << 4)

__global__ __launch_bounds__(512) void k_lstm4(
    const float* __restrict__ feat, const float* __restrict__ w_ih,
    const float* __restrict__ w_hh, const float* __restrict__ b_ih,
    const float* __restrict__ b_hh, float* __restrict__ out, int T)
{
    __shared__ __align__(16) unsigned hx[2][16][128];   // 16 KB, swizzled
    __shared__ __align__(16) u32x4 wlds[8 * 2 * 8 * 64];  // 128 KB, frag order

    const int tid  = threadIdx.x;
    const int bk   = blockIdx.x;          // batches [bk*16, bk*16+16)
    const int wv   = tid >> 6;            // wave 0..7 -> units [wv*16,+16)
    const int lane = tid & 63;
    const int c    = lane & 15;           // batch (B-col / D-col); A-row unit
    const int q    = lane >> 4;           // k-group; D-row quad

    // ---- A-fragments: gates 0,1 -> registers; gates 2,3 -> LDS ----
    bf16x8 afr[2][8];
#pragma unroll
    for (int g = 0; g < 4; ++g) {
        const int row = g * 128 + wv * 16 + c;   // global gate row
#pragma unroll
        for (int ks = 0; ks < 8; ++ks) {
            const int m0 = ks * 16 + q * 4;      // h-index of first pair
            float4 h4 = *reinterpret_cast<const float4*>(w_hh + (size_t)row * 128 + m0);
            float4 i4 = *reinterpret_cast<const float4*>(w_ih + (size_t)row * 128 + m0);
            u32x4 u;
            u.x = (bfr(i4.x) << 16) | bfr(h4.x);
            u.y = (bfr(i4.y) << 16) | bfr(h4.y);
            u.z = (bfr(i4.z) << 16) | bfr(h4.z);
            u.w = (bfr(i4.w) << 16) | bfr(h4.w);
            if (g < 2)
                afr[g][ks] = __builtin_bit_cast(bf16x8, u);
            else
                wlds[((wv * 2 + (g - 2)) * 8 + ks) * 64 + lane] = u;
        }
    }

    // bias for (gate g, unit wv*16 + q*4 + r) — folded into acc init
    float bias[4][4];
#pragma unroll
    for (int g = 0; g < 4; ++g)
#pragma unroll
        for (int r = 0; r < 4; ++r) {
            const int j = wv * 16 + q * 4 + r;
            bias[g][r] = b_ih[g * 128 + j] + b_hh[g * 128 + j];
        }

    const size_t fbase = ((size_t)(bk * 16 + c)) * T;  // this lane's batch
    const int u0 = wv * 16 + q * 4;                    // first owned unit

    // ---- init hx[0]: h=0 (low), x=x(T-1) (high) ----
    {
        float4 x0 = *reinterpret_cast<const float4*>(feat + (fbase + (T - 1)) * 128 + u0);
        u32x4 u;
        u.x = bfr(x0.x) << 16;
        u.y = bfr(x0.y) << 16;
        u.z = bfr(x0.z) << 16;
        u.w = bfr(x0.w) << 16;
        *reinterpret_cast<u32x4*>((char*)&hx[0][c][0] + ((u0 * 4) ^ SWZ(c))) = u;
    }
    f32x4 cst = {0.f, 0.f, 0.f, 0.f};
    __syncthreads();

    int cur = 0;
    for (int t = T - 1; t >= 0; --t) {
        const int tp = (t > 0) ? t - 1 : 0;
        float4 xp = *reinterpret_cast<const float4*>(feat + (fbase + tp) * 128 + u0);

        f32x4 acc0 = {bias[0][0], bias[0][1], bias[0][2], bias[0][3]};
        f32x4 acc1 = {bias[1][0], bias[1][1], bias[1][2], bias[1][3]};
        f32x4 acc2 = {bias[2][0], bias[2][1], bias[2][2], bias[2][3]};
        f32x4 acc3 = {bias[3][0], bias[3][1], bias[3][2], bias[3][3]};

        const char* hrow = (const char*)&hx[cur][c][0];
        const u32x4* wp0 = &wlds[(wv * 2 + 0) * 8 * 64 + lane];
        const u32x4* wp1 = &wlds[(wv * 2 + 1) * 8 * 64 + lane];
#pragma unroll
        for (int ks = 0; ks < 8; ++ks) {
            u32x4 bq = *reinterpret_cast<const u32x4*>(
                hrow + ((ks * 64 + q * 16) ^ SWZ(c)));
            bf16x8 bf = __builtin_bit_cast(bf16x8, bq);
            acc0 = __builtin_amdgcn_mfma_f32_16x16x32_bf16(afr[0][ks], bf, acc0, 0, 0, 0);
            acc1 = __builtin_amdgcn_mfma_f32_16x16x32_bf16(afr[1][ks], bf, acc1, 0, 0, 0);
            bf16x8 a2 = __builtin_bit_cast(bf16x8, wp0[ks * 64]);
            acc2 = __builtin_amdgcn_mfma_f32_16x16x32_bf16(a2, bf, acc2, 0, 0, 0);
            bf16x8 a3 = __builtin_bit_cast(bf16x8, wp1[ks * 64]);
            acc3 = __builtin_amdgcn_mfma_f32_16x16x32_bf16(a3, bf, acc3, 0, 0, 0);
        }

        // ---- in-lane pointwise for (batch c, units u0..u0+3) ----
        float h[4];
#pragma unroll
        for (int r = 0; r < 4; ++r) {
            float gi = sigf(acc0[r]);
            float gf = sigf(acc1[r]);
            float gg = tanhfast(acc2[r]);
            float go = sigf(acc3[r]);
            cst[r] = gf * cst[r] + gi * gg;
            h[r] = go * tanhfast(cst[r]);
        }
        *reinterpret_cast<float4*>(out + (fbase + t) * 128 + u0) =
            make_float4(h[0], h[1], h[2], h[3]);

        u32x4 u;
        u.x = (bfr(xp.x) << 16) | bfr(h[0]);
        u.y = (bfr(xp.y) << 16) | bfr(h[1]);
        u.z = (bfr(xp.z) << 16) | bfr(h[2]);
        u.w = (bfr(xp.w) << 16) | bfr(h[3]);
        *reinterpret_cast<u32x4*>((char*)&hx[cur ^ 1][c][0] + ((u0 * 4) ^ SWZ(c))) = u;

        cur ^= 1;
        __syncthreads();  // hx[cur] complete for next step
    }
}

extern "C" void kernel_launch(void* const* d_in, const int* in_sizes, int n_in,
                              void* d_out, int out_size, void* d_ws, size_t ws_size,
                              hipStream_t stream)
{
    const float* x    = (const float*)d_in[0];
    const float* c1w  = (const float*)d_in[1];
    const float* bn1g = (const float*)d_in[2];
    const float* bn1b = (const float*)d_in[3];
    const float* bn1m = (const float*)d_in[4];
    const float* bn1v = (const float*)d_in[5];
    const float* c2w  = (const float*)d_in[6];
    const float* bn2g = (const float*)d_in[7];
    const float* bn2b = (const float*)d_in[8];
    const float* bn2m = (const float*)d_in[9];
    const float* bn2v = (const float*)d_in[10];
    const float* c3w  = (const float*)d_in[11];
    const float* bn3g = (const float*)d_in[12];
    const float* bn3b = (const float*)d_in[13];
    const float* bn3m = (const float*)d_in[14];
    const float* bn3v = (const float*)d_in[15];
    const float* w_ih = (const float*)d_in[16];
    const float* w_hh = (const float*)d_in[17];
    const float* b_ih = (const float*)d_in[18];
    const float* b_hh = (const float*)d_in[19];
    float* out = (float*)d_out;

    const int B = 64, T = 4096;
    char* ws = (char*)d_ws;
    const size_t sz_y1 = (size_t)B * 32 * T * 4;   // 32 MB
    const size_t sz_y2 = (size_t)B * 64 * T * 4;   // 64 MB

    float* y1   = (float*)ws;
    float* y2   = (float*)(ws + sz_y1);
    float* feat = (float*)(ws + sz_y1 + sz_y2);

    k_conv1<<<dim3(T / 256, B), 256, 0, stream>>>(x, c1w, bn1g, bn1b, bn1m, bn1v, y1, B, T);
    k_conv2<<<dim3(T / 256, B), 256, 0, stream>>>(y1, c2w, bn2g, bn2b, bn2m, bn2v, y2, B, T);
    k_conv3<<<dim3(T / 128, B), 256, 0, stream>>>(y2, c3w, bn3g, bn3b, bn3m, bn3v, feat, B, T);

    k_lstm4<<<dim3(4), 512, 0, stream>>>(feat, w_ih, w_hh, b_ih, b_hh, out, T);
}

// Round 10
// 8761.295 us; speedup vs baseline: 2.0784x; 1.0590x over previous
//
#include <hip/hip_runtime.h>
#include <cstdint>
#include <cstddef>

#define BN_EPS 1e-5f

typedef __attribute__((ext_vector_type(8))) short  bf16x8;
typedef __attribute__((ext_vector_type(4))) float  f32x4;
typedef __attribute__((ext_vector_type(4))) unsigned u32x4;
typedef __attribute__((ext_vector_type(2))) unsigned u32x2;
typedef __attribute__((ext_vector_type(8))) _Float16 f16x8;
typedef __attribute__((ext_vector_type(4))) _Float16 f16x4;

__device__ __forceinline__ float sigf(float x) {
    return 1.0f / (1.0f + __expf(-x));
}
__device__ __forceinline__ float tanhfast(float x) {
    return 2.0f / (1.0f + __expf(-2.0f * x)) - 1.0f;
}
__device__ __forceinline__ unsigned bfr(float x) {  // f32 -> bf16 bits (RNE)
    unsigned u = __float_as_uint(x);
    return (u + 0x7fffu + ((u >> 16) & 1u)) >> 16;
}
__device__ __forceinline__ bf16x8 pack8(float4 a, float4 b) {  // ascending k
    u32x4 u;
    u.x = (bfr(a.y) << 16) | bfr(a.x);
    u.y = (bfr(a.w) << 16) | bfr(a.z);
    u.z = (bfr(b.y) << 16) | bfr(b.x);
    u.w = (bfr(b.w) << 16) | bfr(b.z);
    return __builtin_bit_cast(bf16x8, u);
}

// ---------------- conv1 + BN + ReLU : x[B,T,9] -> y1[B,32,T] ----------------
__global__ __launch_bounds__(256) void k_conv1(
    const float* __restrict__ x, const float* __restrict__ w,
    const float* __restrict__ g, const float* __restrict__ bb,
    const float* __restrict__ m, const float* __restrict__ v,
    float* __restrict__ y1, int B, int T)
{
    const int TT = 256;
    __shared__ float xs[(TT + 6) * 9];
    const int b = blockIdx.y;
    const int t0 = blockIdx.x * TT;
    const int tid = threadIdx.x;

    for (int idx = tid; idx < (TT + 6) * 9; idx += 256) {
        int row = idx / 9, col = idx - row * 9;
        int tg = t0 - 3 + row;
        xs[idx] = (tg >= 0 && tg < T) ? x[((size_t)b * T + tg) * 9 + col] : 0.0f;
    }
    __syncthreads();

    float xv[63];
#pragma unroll
    for (int k = 0; k < 7; ++k)
#pragma unroll
        for (int ci = 0; ci < 9; ++ci)
            xv[k * 9 + ci] = xs[(tid + k) * 9 + ci];

    const int t = t0 + tid;
    for (int co = 0; co < 32; ++co) {
        float acc = 0.0f;
#pragma unroll
        for (int ci = 0; ci < 9; ++ci)
#pragma unroll
            for (int k = 0; k < 7; ++k)
                acc += xv[k * 9 + ci] * w[(co * 9 + ci) * 7 + k];
        float sc = g[co] / sqrtf(v[co] + BN_EPS);
        float bf = bb[co] - m[co] * sc;
        float o = acc * sc + bf;
        y1[((size_t)b * 32 + co) * T + t] = o > 0.0f ? o : 0.0f;
    }
}

// ---------------- conv2 + BN + ReLU : y1[B,32,T] -> y2[B,64,T] --------------
__global__ __launch_bounds__(256) void k_conv2(
    const float* __restrict__ y1, const float* __restrict__ w,
    const float* __restrict__ g, const float* __restrict__ bb,
    const float* __restrict__ m, const float* __restrict__ v,
    float* __restrict__ y2, int B, int T)
{
    const int TT = 256;
    __shared__ float ys[32 * (TT + 6)];
    const int b = blockIdx.y;
    const int t0 = blockIdx.x * TT;
    const int tid = threadIdx.x;

    for (int idx = tid; idx < 32 * (TT + 6); idx += 256) {
        int ci = idx / (TT + 6), i = idx - ci * (TT + 6);
        int tg = t0 - 3 + i;
        ys[idx] = (tg >= 0 && tg < T) ? y1[((size_t)b * 32 + ci) * T + tg] : 0.0f;
    }
    __syncthreads();

    float acc[64];
#pragma unroll
    for (int co = 0; co < 64; ++co) acc[co] = 0.0f;

    for (int ci = 0; ci < 32; ++ci) {
        float yw[7];
#pragma unroll
        for (int k = 0; k < 7; ++k) yw[k] = ys[ci * (TT + 6) + tid + k];
#pragma unroll
        for (int co = 0; co < 64; ++co)
#pragma unroll
            for (int k = 0; k < 7; ++k)
                acc[co] += yw[k] * w[(co * 32 + ci) * 7 + k];
    }

    const int t = t0 + tid;
    for (int co = 0; co < 64; ++co) {
        float sc = g[co] / sqrtf(v[co] + BN_EPS);
        float bf = bb[co] - m[co] * sc;
        float o = acc[co] * sc + bf;
        y2[((size_t)b * 64 + co) * T + t] = o > 0.0f ? o : 0.0f;
    }
}

// ------------- conv3 + BN + ReLU : y2[B,64,T] -> feat[B,T,128] --------------
__global__ __launch_bounds__(256) void k_conv3(
    const float* __restrict__ y2, const float* __restrict__ w,
    const float* __restrict__ g, const float* __restrict__ bb,
    const float* __restrict__ m, const float* __restrict__ v,
    float* __restrict__ feat, int B, int T)
{
    const int TT = 128;
    __shared__ float ys[64 * (TT + 6)];
    const int b = blockIdx.y;
    const int t0 = blockIdx.x * TT;
    const int tid = threadIdx.x;
    const int tl = tid & 127;
    const int half = __builtin_amdgcn_readfirstlane(tid >> 7);  // wave-uniform

    for (int idx = tid; idx < 64 * (TT + 6); idx += 256) {
        int ci = idx / (TT + 6), i = idx - ci * (TT + 6);
        int tg = t0 - 3 + i;
        ys[idx] = (tg >= 0 && tg < T) ? y2[((size_t)b * 64 + ci) * T + tg] : 0.0f;
    }
    __syncthreads();

    float acc[64];
#pragma unroll
    for (int q = 0; q < 64; ++q) acc[q] = 0.0f;

    for (int ci = 0; ci < 64; ++ci) {
        float yw[7];
#pragma unroll
        for (int k = 0; k < 7; ++k) yw[k] = ys[ci * (TT + 6) + tl + k];
#pragma unroll
        for (int q = 0; q < 64; ++q)
#pragma unroll
            for (int k = 0; k < 7; ++k)
                acc[q] += yw[k] * w[((half * 64 + q) * 64 + ci) * 7 + k];
    }

    const int t = t0 + tl;
    for (int q = 0; q < 64; ++q) {
        int co = half * 64 + q;
        float sc = g[co] / sqrtf(v[co] + BN_EPS);
        float bf = bb[co] - m[co] * sc;
        float o = acc[q] * sc + bf;
        feat[((size_t)b * T + t) * 128 + co] = o > 0.0f ? o : 0.0f;
    }
}

// ----------- x-projection GEMM: xp = W_ih·x + b_ih + b_hh (f16) -------------
// Grid (T/32, B), 256 thr = 4 waves. Wave wv2 = gate wv2; per block: one batch,
// 32 timesteps, all 512 gate-rows. M=512,N=32,K=128 bf16 MFMA.
// Output layout matches LSTM lanes: xp[(b*T+t)*512 + (u>>2)*16 + g*4 + (u&3)].
__global__ __launch_bounds__(256) void k_xpre(
    const float* __restrict__ feat, const float* __restrict__ w_ih,
    const float* __restrict__ b_ih, const float* __restrict__ b_hh,
    _Float16* __restrict__ xp, int T)
{
    const int b   = blockIdx.y;
    const int t0  = blockIdx.x * 32;
    const int tid = threadIdx.x;
    const int wv2 = tid >> 6;      // gate g
    const int lane = tid & 63;
    const int c2 = lane & 15;
    const int q2 = lane >> 4;

    // B-frags: x[t0+tc*16+c2][ks*32+q2*8 .. +8] as bf16
    bf16x8 btile[2][4];
#pragma unroll
    for (int tc = 0; tc < 2; ++tc) {
        const float* xrow = feat + ((size_t)b * T + t0 + tc * 16 + c2) * 128;
#pragma unroll
        for (int ks = 0; ks < 4; ++ks) {
            float4 x0 = *reinterpret_cast<const float4*>(xrow + ks * 32 + q2 * 8);
            float4 x1 = *reinterpret_cast<const float4*>(xrow + ks * 32 + q2 * 8 + 4);
            btile[tc][ks] = pack8(x0, x1);
        }
    }

#pragma unroll
    for (int rt = 0; rt < 8; ++rt) {
        const int row = wv2 * 128 + rt * 16 + c2;   // gate-row for A lane
        bf16x8 a[4];
#pragma unroll
        for (int ks = 0; ks < 4; ++ks) {
            float4 w0 = *reinterpret_cast<const float4*>(w_ih + (size_t)row * 128 + ks * 32 + q2 * 8);
            float4 w1 = *reinterpret_cast<const float4*>(w_ih + (size_t)row * 128 + ks * 32 + q2 * 8 + 4);
            a[ks] = pack8(w0, w1);
        }
        const int gr0 = wv2 * 128 + rt * 16 + q2 * 4;  // D rows this lane owns
        float4 bi = *reinterpret_cast<const float4*>(b_ih + gr0);
        float4 bh = *reinterpret_cast<const float4*>(b_hh + gr0);
        f32x4 bias = {bi.x + bh.x, bi.y + bh.y, bi.z + bh.z, bi.w + bh.w};

#pragma unroll
        for (int tc = 0; tc < 2; ++tc) {
            f32x4 acc = bias;
#pragma unroll
            for (int ks = 0; ks < 4; ++ks)
                acc = __builtin_amdgcn_mfma_f32_16x16x32_bf16(a[ks], btile[tc][ks], acc, 0, 0, 0);
            const int t = t0 + tc * 16 + c2;          // D col = lane&15
            f16x4 hv = {(_Float16)acc[0], (_Float16)acc[1],
                        (_Float16)acc[2], (_Float16)acc[3]};
            // u = rt*16 + q2*4 + r ; u>>2 = rt*4+q2 ; g = wv2 ; u&3 = r
            *reinterpret_cast<f16x4*>(
                xp + ((size_t)b * T + t) * 512 + (rt * 4 + q2) * 16 + wv2 * 4) = hv;
        }
    }
}

// --------------------- reversed-time LSTM (MFMA, K=128) ---------------------
// 4 blocks x 16 batches, 512 thr = 8 waves. Wave wv owns units [wv*16,+16),
// 4 gate-tiles, ALL A-frags in registers (afr[4][4] = 64 VGPR; K=128 since x
// was precomputed into xp). D-frag in-lane pointwise (R9-validated mapping).
// Per-step LDS: 4 b128 h reads + one 8B h write per thread. One barrier/step
// (double-buffered h). xp prefetched one step ahead (16 f16 = 8 VGPR).
#define SWZ(b) (((b) & 7) << 4)

__global__ __launch_bounds__(512) void k_lstm5(
    const _Float16* __restrict__ xp, const float* __restrict__ w_hh,
    float* __restrict__ out, int T)
{
    __shared__ __align__(16) unsigned short h_lds[2][16][128];  // bf16, 8 KB

    const int tid  = threadIdx.x;
    const int bk   = blockIdx.x;
    const int wv   = tid >> 6;
    const int lane = tid & 63;
    const int c    = lane & 15;
    const int q    = lane >> 4;
    const int u0   = wv * 16 + q * 4;
    const int b    = bk * 16 + c;

    // A-frags: W_hh[g*128 + wv*16 + c][ks*32+q*8 .. +8] bf16 (64 VGPR)
    bf16x8 afr[4][4];
#pragma unroll
    for (int g = 0; g < 4; ++g) {
        const float* wr = w_hh + (size_t)(g * 128 + wv * 16 + c) * 128;
#pragma unroll
        for (int ks = 0; ks < 4; ++ks) {
            float4 w0 = *reinterpret_cast<const float4*>(wr + ks * 32 + q * 8);
            float4 w1 = *reinterpret_cast<const float4*>(wr + ks * 32 + q * 8 + 4);
            afr[g][ks] = pack8(w0, w1);
        }
    }

    // init h(T) = 0 : this thread owns (batch c, units u0..u0+3)
    {
        u32x2 z = {0u, 0u};
        *reinterpret_cast<u32x2*>(
            (char*)&h_lds[0][c][0] + ((u0 * 2) ^ SWZ(c))) = z;
    }
    f32x4 cst = {0.f, 0.f, 0.f, 0.f};

    // xp prefetch: this lane's 16 contiguous f16 per step
    const _Float16* xpb = xp + ((size_t)b * T) * 512 + (wv * 4 + q) * 16;
    f16x8 P0 = *reinterpret_cast<const f16x8*>(xpb + (size_t)(T - 1) * 512);
    f16x8 P1 = *reinterpret_cast<const f16x8*>(xpb + (size_t)(T - 1) * 512 + 8);
    __syncthreads();

    int cur = 0;
    for (int t = T - 1; t >= 0; --t) {
        // acc init from xp(t): [g0 r0..3 | g1 r0..3 | g2 r0..3 | g3 r0..3]
        f32x4 acc0 = {(float)P0[0], (float)P0[1], (float)P0[2], (float)P0[3]};
        f32x4 acc1 = {(float)P0[4], (float)P0[5], (float)P0[6], (float)P0[7]};
        f32x4 acc2 = {(float)P1[0], (float)P1[1], (float)P1[2], (float)P1[3]};
        f32x4 acc3 = {(float)P1[4], (float)P1[5], (float)P1[6], (float)P1[7]};
        // issue next prefetch (consumed next iteration)
        const int tp = (t > 0) ? t - 1 : 0;
        P0 = *reinterpret_cast<const f16x8*>(xpb + (size_t)tp * 512);
        P1 = *reinterpret_cast<const f16x8*>(xpb + (size_t)tp * 512 + 8);

        const char* hrow = (const char*)&h_lds[cur][c][0];
#pragma unroll
        for (int ks = 0; ks < 4; ++ks) {
            u32x4 bq = *reinterpret_cast<const u32x4*>(
                hrow + ((ks * 64 + q * 16) ^ SWZ(c)));
            bf16x8 bf = __builtin_bit_cast(bf16x8, bq);
            acc0 = __builtin_amdgcn_mfma_f32_16x16x32_bf16(afr[0][ks], bf, acc0, 0, 0, 0);
            acc1 = __builtin_amdgcn_mfma_f32_16x16x32_bf16(afr[1][ks], bf, acc1, 0, 0, 0);
            acc2 = __builtin_amdgcn_mfma_f32_16x16x32_bf16(afr[2][ks], bf, acc2, 0, 0, 0);
            acc3 = __builtin_amdgcn_mfma_f32_16x16x32_bf16(afr[3][ks], bf, acc3, 0, 0, 0);
        }

        float h[4];
#pragma unroll
        for (int r = 0; r < 4; ++r) {
            float gi = sigf(acc0[r]);
            float gf = sigf(acc1[r]);
            float gg = tanhfast(acc2[r]);
            float go = sigf(acc3[r]);
            cst[r] = gf * cst[r] + gi * gg;
            h[r] = go * tanhfast(cst[r]);
        }
        *reinterpret_cast<float4*>(out + ((size_t)b * T + t) * 128 + u0) =
            make_float4(h[0], h[1], h[2], h[3]);

        u32x2 hw;
        hw.x = (bfr(h[1]) << 16) | bfr(h[0]);
        hw.y = (bfr(h[3]) << 16) | bfr(h[2]);
        *reinterpret_cast<u32x2*>(
            (char*)&h_lds[cur ^ 1][c][0] + ((u0 * 2) ^ SWZ(c))) = hw;

        cur ^= 1;
        __syncthreads();
    }
}

// ------------------- fallback LSTM (R9, K=256 interleaved) ------------------
__global__ __launch_bounds__(512) void k_lstm4(
    const float* __restrict__ feat, const float* __restrict__ w_ih,
    const float* __restrict__ w_hh, const float* __restrict__ b_ih,
    const float* __restrict__ b_hh, float* __restrict__ out, int T)
{
    __shared__ __align__(16) unsigned hx[2][16][128];
    __shared__ __align__(16) u32x4 wlds[8 * 2 * 8 * 64];

    const int tid  = threadIdx.x;
    const int bk   = blockIdx.x;
    const int wv   = tid >> 6;
    const int lane = tid & 63;
    const int c    = lane & 15;
    const int q    = lane >> 4;

    bf16x8 afr[2][8];
#pragma unroll
    for (int g = 0; g < 4; ++g) {
        const int row = g * 128 + wv * 16 + c;
#pragma unroll
        for (int ks = 0; ks < 8; ++ks) {
            const int m0 = ks * 16 + q * 4;
            float4 h4 = *reinterpret_cast<const float4*>(w_hh + (size_t)row * 128 + m0);
            float4 i4 = *reinterpret_cast<const float4*>(w_ih + (size_t)row * 128 + m0);
            u32x4 u;
            u.x = (bfr(i4.x) << 16) | bfr(h4.x);
            u.y = (bfr(i4.y) << 16) | bfr(h4.y);
            u.z = (bfr(i4.z) << 16) | bfr(h4.z);
            u.w = (bfr(i4.w) << 16) | bfr(h4.w);
            if (g < 2)
                afr[g][ks] = __builtin_bit_cast(bf16x8, u);
            else
                wlds[((wv * 2 + (g - 2)) * 8 + ks) * 64 + lane] = u;
        }
    }

    float bias[4][4];
#pragma unroll
    for (int g = 0; g < 4; ++g)
#pragma unroll
        for (int r = 0; r < 4; ++r) {
            const int j = wv * 16 + q * 4 + r;
            bias[g][r] = b_ih[g * 128 + j] + b_hh[g * 128 + j];
        }

    const size_t fbase = ((size_t)(bk * 16 + c)) * T;
    const int u0 = wv * 16 + q * 4;

    {
        float4 x0 = *reinterpret_cast<const float4*>(feat + (fbase + (T - 1)) * 128 + u0);
        u32x4 u;
        u.x = bfr(x0.x) << 16;
        u.y = bfr(x0.y) << 16;
        u.z = bfr(x0.z) << 16;
        u.w = bfr(x0.w) << 16;
        *reinterpret_cast<u32x4*>((char*)&hx[0][c][0] + ((u0 * 4) ^ SWZ(c))) = u;
    }
    f32x4 cst = {0.f, 0.f, 0.f, 0.f};
    __syncthreads();

    int cur = 0;
    for (int t = T - 1; t >= 0; --t) {
        const int tp = (t > 0) ? t - 1 : 0;
        float4 xpv = *reinterpret_cast<const float4*>(feat + (fbase + tp) * 128 + u0);

        f32x4 acc0 = {bias[0][0], bias[0][1], bias[0][2], bias[0][3]};
        f32x4 acc1 = {bias[1][0], bias[1][1], bias[1][2], bias[1][3]};
        f32x4 acc2 = {bias[2][0], bias[2][1], bias[2][2], bias[2][3]};
        f32x4 acc3 = {bias[3][0], bias[3][1], bias[3][2], bias[3][3]};

        const char* hrow = (const char*)&hx[cur][c][0];
        const u32x4* wp0 = &wlds[(wv * 2 + 0) * 8 * 64 + lane];
        const u32x4* wp1 = &wlds[(wv * 2 + 1) * 8 * 64 + lane];
#pragma unroll
        for (int ks = 0; ks < 8; ++ks) {
            u32x4 bq = *reinterpret_cast<const u32x4*>(
                hrow + ((ks * 64 + q * 16) ^ SWZ(c)));
            bf16x8 bf = __builtin_bit_cast(bf16x8, bq);
            acc0 = __builtin_amdgcn_mfma_f32_16x16x32_bf16(afr[0][ks], bf, acc0, 0, 0, 0);
            acc1 = __builtin_amdgcn_mfma_f32_16x16x32_bf16(afr[1][ks], bf, acc1, 0, 0, 0);
            bf16x8 a2 = __builtin_bit_cast(bf16x8, wp0[ks * 64]);
            acc2 = __builtin_amdgcn_mfma_f32_16x16x32_bf16(a2, bf, acc2, 0, 0, 0);
            bf16x8 a3 = __builtin_bit_cast(bf16x8, wp1[ks * 64]);
            acc3 = __builtin_amdgcn_mfma_f32_16x16x32_bf16(a3, bf, acc3, 0, 0, 0);
        }

        float h[4];
#pragma unroll
        for (int r = 0; r < 4; ++r) {
            float gi = sigf(acc0[r]);
            float gf = sigf(acc1[r]);
            float gg = tanhfast(acc2[r]);
            float go = sigf(acc3[r]);
            cst[r] = gf * cst[r] + gi * gg;
            h[r] = go * tanhfast(cst[r]);
        }
        *reinterpret_cast<float4*>(out + (fbase + t) * 128 + u0) =
            make_float4(h[0], h[1], h[2], h[3]);

        u32x4 u;
        u.x = (bfr(xpv.x) << 16) | bfr(h[0]);
        u.y = (bfr(xpv.y) << 16) | bfr(h[1]);
        u.z = (bfr(xpv.z) << 16) | bfr(h[2]);
        u.w = (bfr(xpv.w) << 16) | bfr(h[3]);
        *reinterpret_cast<u32x4*>((char*)&hx[cur ^ 1][c][0] + ((u0 * 4) ^ SWZ(c))) = u;

        cur ^= 1;
        __syncthreads();
    }
}

extern "C" void kernel_launch(void* const* d_in, const int* in_sizes, int n_in,
                              void* d_out, int out_size, void* d_ws, size_t ws_size,
                              hipStream_t stream)
{
    const float* x    = (const float*)d_in[0];
    const float* c1w  = (const float*)d_in[1];
    const float* bn1g = (const float*)d_in[2];
    const float* bn1b = (const float*)d_in[3];
    const float* bn1m = (const float*)d_in[4];
    const float* bn1v = (const float*)d_in[5];
    const float* c2w  = (const float*)d_in[6];
    const float* bn2g = (const float*)d_in[7];
    const float* bn2b = (const float*)d_in[8];
    const float* bn2m = (const float*)d_in[9];
    const float* bn2v = (const float*)d_in[10];
    const float* c3w  = (const float*)d_in[11];
    const float* bn3g = (const float*)d_in[12];
    const float* bn3b = (const float*)d_in[13];
    const float* bn3m = (const float*)d_in[14];
    const float* bn3v = (const float*)d_in[15];
    const float* w_ih = (const float*)d_in[16];
    const float* w_hh = (const float*)d_in[17];
    const float* b_ih = (const float*)d_in[18];
    const float* b_hh = (const float*)d_in[19];
    float* out = (float*)d_out;

    const int B = 64, T = 4096;
    char* ws = (char*)d_ws;
    const size_t sz_y1 = (size_t)B * 32 * T * 4;        //  32 MB
    const size_t sz_y2 = (size_t)B * 64 * T * 4;        //  64 MB
    const size_t sz_xp = (size_t)B * T * 512 * 2;       // 256 MB (f16)

    const bool fast = ws_size >= sz_y2 + sz_xp;         // 320 MB

    if (fast) {
        // y1 and feat live in d_out (each dead before overwrite); y2+xp in ws.
        float* y1   = (float*)d_out;            // 32 MB of d_out
        float* y2   = (float*)ws;               // ws[0, 64MB)
        float* feat = (float*)d_out;            // d_out reused (y1 dead)
        _Float16* xp = (_Float16*)(ws + sz_y2); // ws[64, 320MB)

        k_conv1<<<dim3(T / 256, B), 256, 0, stream>>>(x, c1w, bn1g, bn1b, bn1m, bn1v, y1, B, T);
        k_conv2<<<dim3(T / 256, B), 256, 0, stream>>>(y1, c2w, bn2g, bn2b, bn2m, bn2v, y2, B, T);
        k_conv3<<<dim3(T / 128, B), 256, 0, stream>>>(y2, c3w, bn3g, bn3b, bn3m, bn3v, feat, B, T);
        k_xpre<<<dim3(T / 32, B), 256, 0, stream>>>(feat, w_ih, b_ih, b_hh, xp, T);
        k_lstm5<<<dim3(4), 512, 0, stream>>>(xp, w_hh, out, T);
    } else {
        float* y1   = (float*)ws;
        float* y2   = (float*)(ws + sz_y1);
        float* feat = (float*)(ws + sz_y1 + sz_y2);

        k_conv1<<<dim3(T / 256, B), 256, 0, stream>>>(x, c1w, bn1g, bn1b, bn1m, bn1v, y1, B, T);
        k_conv2<<<dim3(T / 256, B), 256, 0, stream>>>(y1, c2w, bn2g, bn2b, bn2m, bn2v, y2, B, T);
        k_conv3<<<dim3(T / 128, B), 256, 0, stream>>>(y2, c3w, bn3g, bn3b, bn3m, bn3v, feat, B, T);
        k_lstm4<<<dim3(4), 512, 0, stream>>>(feat, w_ih, w_hh, b_ih, b_hh, out, T);
    }
}

// Round 12
// 7333.387 us; speedup vs baseline: 2.4831x; 1.1947x over previous
//
#include <hip/hip_runtime.h>
#include <cstdint>
#include <cstddef>

#define BN_EPS 1e-5f
#define L2E   1.4426950408889634f
#define L2E2  2.8853900817779268f

typedef __attribute__((ext_vector_type(8))) short  bf16x8;
typedef __attribute__((ext_vector_type(4))) float  f32x4;
typedef __attribute__((ext_vector_type(4))) unsigned u32x4;
typedef __attribute__((ext_vector_type(2))) unsigned u32x2;
typedef __attribute__((ext_vector_type(8))) _Float16 f16x8;
typedef __attribute__((ext_vector_type(4))) _Float16 f16x4;

__device__ __forceinline__ float sigf(float x) {
    return 1.0f / (1.0f + __expf(-x));
}
__device__ __forceinline__ float tanhfast(float x) {
    return 2.0f / (1.0f + __expf(-2.0f * x)) - 1.0f;
}
__device__ __forceinline__ unsigned bfr(float x) {  // f32 -> bf16 bits (RNE)
    unsigned u = __float_as_uint(x);
    return (u + 0x7fffu + ((u >> 16) & 1u)) >> 16;
}
__device__ __forceinline__ bf16x8 pack8(float4 a, float4 b) {  // ascending k
    u32x4 u;
    u.x = (bfr(a.y) << 16) | bfr(a.x);
    u.y = (bfr(a.w) << 16) | bfr(a.z);
    u.z = (bfr(b.y) << 16) | bfr(b.x);
    u.w = (bfr(b.w) << 16) | bfr(b.z);
    return __builtin_bit_cast(bf16x8, u);
}
// fast HW ops via INTRINSICS (R11 lesson: raw inline-asm v_rcp/v_exp read
// stale registers — trans-op hazard nops are not inserted around INLINEASM;
// builtins emit the same instructions with correct hazard handling)
__device__ __forceinline__ float rcp_f(float x) {
    return __builtin_amdgcn_rcpf(x);
}
__device__ __forceinline__ float exp2_f(float x) {
    return __builtin_amdgcn_exp2f(x);
}
__device__ __forceinline__ unsigned cvtpk_bf16(float lo, float hi) {
    unsigned r; asm("v_cvt_pk_bf16_f32 %0, %1, %2" : "=v"(r) : "v"(lo), "v"(hi));
    return r;
}

// ---------------- conv1 + BN + ReLU : x[B,T,9] -> y1[B,32,T] ----------------
__global__ __launch_bounds__(256) void k_conv1(
    const float* __restrict__ x, const float* __restrict__ w,
    const float* __restrict__ g, const float* __restrict__ bb,
    const float* __restrict__ m, const float* __restrict__ v,
    float* __restrict__ y1, int B, int T)
{
    const int TT = 256;
    __shared__ float xs[(TT + 6) * 9];
    const int b = blockIdx.y;
    const int t0 = blockIdx.x * TT;
    const int tid = threadIdx.x;

    for (int idx = tid; idx < (TT + 6) * 9; idx += 256) {
        int row = idx / 9, col = idx - row * 9;
        int tg = t0 - 3 + row;
        xs[idx] = (tg >= 0 && tg < T) ? x[((size_t)b * T + tg) * 9 + col] : 0.0f;
    }
    __syncthreads();

    float xv[63];
#pragma unroll
    for (int k = 0; k < 7; ++k)
#pragma unroll
        for (int ci = 0; ci < 9; ++ci)
            xv[k * 9 + ci] = xs[(tid + k) * 9 + ci];

    const int t = t0 + tid;
    for (int co = 0; co < 32; ++co) {
        float acc = 0.0f;
#pragma unroll
        for (int ci = 0; ci < 9; ++ci)
#pragma unroll
            for (int k = 0; k < 7; ++k)
                acc += xv[k * 9 + ci] * w[(co * 9 + ci) * 7 + k];
        float sc = g[co] / sqrtf(v[co] + BN_EPS);
        float bf = bb[co] - m[co] * sc;
        float o = acc * sc + bf;
        y1[((size_t)b * 32 + co) * T + t] = o > 0.0f ? o : 0.0f;
    }
}

// ---------------- conv2 + BN + ReLU : y1[B,32,T] -> y2[B,64,T] --------------
__global__ __launch_bounds__(256) void k_conv2(
    const float* __restrict__ y1, const float* __restrict__ w,
    const float* __restrict__ g, const float* __restrict__ bb,
    const float* __restrict__ m, const float* __restrict__ v,
    float* __restrict__ y2, int B, int T)
{
    const int TT = 256;
    __shared__ float ys[32 * (TT + 6)];
    const int b = blockIdx.y;
    const int t0 = blockIdx.x * TT;
    const int tid = threadIdx.x;

    for (int idx = tid; idx < 32 * (TT + 6); idx += 256) {
        int ci = idx / (TT + 6), i = idx - ci * (TT + 6);
        int tg = t0 - 3 + i;
        ys[idx] = (tg >= 0 && tg < T) ? y1[((size_t)b * 32 + ci) * T + tg] : 0.0f;
    }
    __syncthreads();

    float acc[64];
#pragma unroll
    for (int co = 0; co < 64; ++co) acc[co] = 0.0f;

    for (int ci = 0; ci < 32; ++ci) {
        float yw[7];
#pragma unroll
        for (int k = 0; k < 7; ++k) yw[k] = ys[ci * (TT + 6) + tid + k];
#pragma unroll
        for (int co = 0; co < 64; ++co)
#pragma unroll
            for (int k = 0; k < 7; ++k)
                acc[co] += yw[k] * w[(co * 32 + ci) * 7 + k];
    }

    const int t = t0 + tid;
    for (int co = 0; co < 64; ++co) {
        float sc = g[co] / sqrtf(v[co] + BN_EPS);
        float bf = bb[co] - m[co] * sc;
        float o = acc[co] * sc + bf;
        y2[((size_t)b * 64 + co) * T + t] = o > 0.0f ? o : 0.0f;
    }
}

// ------------- conv3 + BN + ReLU : y2[B,64,T] -> feat[B,T,128] --------------
__global__ __launch_bounds__(256) void k_conv3(
    const float* __restrict__ y2, const float* __restrict__ w,
    const float* __restrict__ g, const float* __restrict__ bb,
    const float* __restrict__ m, const float* __restrict__ v,
    float* __restrict__ feat, int B, int T)
{
    const int TT = 128;
    __shared__ float ys[64 * (TT + 6)];
    const int b = blockIdx.y;
    const int t0 = blockIdx.x * TT;
    const int tid = threadIdx.x;
    const int tl = tid & 127;
    const int half = __builtin_amdgcn_readfirstlane(tid >> 7);  // wave-uniform

    for (int idx = tid; idx < 64 * (TT + 6); idx += 256) {
        int ci = idx / (TT + 6), i = idx - ci * (TT + 6);
        int tg = t0 - 3 + i;
        ys[idx] = (tg >= 0 && tg < T) ? y2[((size_t)b * 64 + ci) * T + tg] : 0.0f;
    }
    __syncthreads();

    float acc[64];
#pragma unroll
    for (int q = 0; q < 64; ++q) acc[q] = 0.0f;

    for (int ci = 0; ci < 64; ++ci) {
        float yw[7];
#pragma unroll
        for (int k = 0; k < 7; ++k) yw[k] = ys[ci * (TT + 6) + tl + k];
#pragma unroll
        for (int q = 0; q < 64; ++q)
#pragma unroll
            for (int k = 0; k < 7; ++k)
                acc[q] += yw[k] * w[((half * 64 + q) * 64 + ci) * 7 + k];
    }

    const int t = t0 + tl;
    for (int q = 0; q < 64; ++q) {
        int co = half * 64 + q;
        float sc = g[co] / sqrtf(v[co] + BN_EPS);
        float bf = bb[co] - m[co] * sc;
        float o = acc[q] * sc + bf;
        feat[((size_t)b * T + t) * 128 + co] = o > 0.0f ? o : 0.0f;
    }
}

// ----------- x-projection GEMM: xp = scale_g*(W_ih·x + b) (f16) -------------
// Per-gate scale folded in: gates i,f,o -> -log2e; gate g -> +2*log2e, so the
// LSTM pointwise can use raw exp2 with zero range-conversion muls.
__global__ __launch_bounds__(256) void k_xpre(
    const float* __restrict__ feat, const float* __restrict__ w_ih,
    const float* __restrict__ b_ih, const float* __restrict__ b_hh,
    _Float16* __restrict__ xp, int T)
{
    const int b   = blockIdx.y;
    const int t0  = blockIdx.x * 32;
    const int tid = threadIdx.x;
    const int wv2 = tid >> 6;      // gate g
    const int lane = tid & 63;
    const int c2 = lane & 15;
    const int q2 = lane >> 4;
    const float sc = (wv2 == 2) ? L2E2 : -L2E;

    bf16x8 btile[2][4];
#pragma unroll
    for (int tc = 0; tc < 2; ++tc) {
        const float* xrow = feat + ((size_t)b * T + t0 + tc * 16 + c2) * 128;
#pragma unroll
        for (int ks = 0; ks < 4; ++ks) {
            float4 x0 = *reinterpret_cast<const float4*>(xrow + ks * 32 + q2 * 8);
            float4 x1 = *reinterpret_cast<const float4*>(xrow + ks * 32 + q2 * 8 + 4);
            btile[tc][ks] = pack8(x0, x1);
        }
    }

#pragma unroll
    for (int rt = 0; rt < 8; ++rt) {
        const int row = wv2 * 128 + rt * 16 + c2;
        bf16x8 a[4];
#pragma unroll
        for (int ks = 0; ks < 4; ++ks) {
            float4 w0 = *reinterpret_cast<const float4*>(w_ih + (size_t)row * 128 + ks * 32 + q2 * 8);
            float4 w1 = *reinterpret_cast<const float4*>(w_ih + (size_t)row * 128 + ks * 32 + q2 * 8 + 4);
            w0.x *= sc; w0.y *= sc; w0.z *= sc; w0.w *= sc;
            w1.x *= sc; w1.y *= sc; w1.z *= sc; w1.w *= sc;
            a[ks] = pack8(w0, w1);
        }
        const int gr0 = wv2 * 128 + rt * 16 + q2 * 4;
        float4 bi = *reinterpret_cast<const float4*>(b_ih + gr0);
        float4 bh = *reinterpret_cast<const float4*>(b_hh + gr0);
        f32x4 bias = {(bi.x + bh.x) * sc, (bi.y + bh.y) * sc,
                      (bi.z + bh.z) * sc, (bi.w + bh.w) * sc};

#pragma unroll
        for (int tc = 0; tc < 2; ++tc) {
            f32x4 acc = bias;
#pragma unroll
            for (int ks = 0; ks < 4; ++ks)
                acc = __builtin_amdgcn_mfma_f32_16x16x32_bf16(a[ks], btile[tc][ks], acc, 0, 0, 0);
            const int t = t0 + tc * 16 + c2;
            f16x4 hv = {(_Float16)acc[0], (_Float16)acc[1],
                        (_Float16)acc[2], (_Float16)acc[3]};
            *reinterpret_cast<f16x4*>(
                xp + ((size_t)b * T + t) * 512 + (rt * 4 + q2) * 16 + wv2 * 4) = hv;
        }
    }
}

// --------------------- reversed-time LSTM (MFMA, K=128) ---------------------
// 4 blocks x 16 batches, 512 thr = 8 waves. A-frags (W_hh, per-gate scale
// folded) fully register-resident. Pointwise ~4 ops/gate via rcp/exp2
// intrinsics. t-loop unrolled x2; xp prefetched 2 steps deep.
#define SWZ(b) (((b) & 7) << 4)

#define LSTM_BODY(TCUR, RBUF, WBUF, Q0, Q1, PFT)                              \
    {                                                                          \
        f32x4 acc0 = {(float)Q0[0], (float)Q0[1], (float)Q0[2], (float)Q0[3]}; \
        f32x4 acc1 = {(float)Q0[4], (float)Q0[5], (float)Q0[6], (float)Q0[7]}; \
        f32x4 acc2 = {(float)Q1[0], (float)Q1[1], (float)Q1[2], (float)Q1[3]}; \
        f32x4 acc3 = {(float)Q1[4], (float)Q1[5], (float)Q1[6], (float)Q1[7]}; \
        const int pt_ = ((PFT) >= 0) ? (PFT) : 0;                              \
        Q0 = *reinterpret_cast<const f16x8*>(xpb + (size_t)pt_ * 512);         \
        Q1 = *reinterpret_cast<const f16x8*>(xpb + (size_t)pt_ * 512 + 8);     \
        const char* hrow_ = (const char*)&RBUF[c][0];                          \
        _Pragma("unroll")                                                      \
        for (int ks = 0; ks < 4; ++ks) {                                       \
            u32x4 bq = *reinterpret_cast<const u32x4*>(                        \
                hrow_ + ((ks * 64 + q * 16) ^ SWZ(c)));                        \
            bf16x8 bf = __builtin_bit_cast(bf16x8, bq);                        \
            acc0 = __builtin_amdgcn_mfma_f32_16x16x32_bf16(afr[0][ks], bf, acc0, 0, 0, 0); \
            acc1 = __builtin_amdgcn_mfma_f32_16x16x32_bf16(afr[1][ks], bf, acc1, 0, 0, 0); \
            acc2 = __builtin_amdgcn_mfma_f32_16x16x32_bf16(afr[2][ks], bf, acc2, 0, 0, 0); \
            acc3 = __builtin_amdgcn_mfma_f32_16x16x32_bf16(afr[3][ks], bf, acc3, 0, 0, 0); \
        }                                                                      \
        float h4_[4];                                                          \
        _Pragma("unroll")                                                      \
        for (int r = 0; r < 4; ++r) {                                          \
            float gi = rcp_f(1.0f + exp2_f(acc0[r]));                          \
            float gf = rcp_f(1.0f + exp2_f(acc1[r]));                          \
            float gg = fmaf(-2.0f, rcp_f(1.0f + exp2_f(acc2[r])), 1.0f);       \
            float go = rcp_f(1.0f + exp2_f(acc3[r]));                          \
            cst[r] = fmaf(gf, cst[r], gi * gg);                                \
            float tc_ = fmaf(-2.0f, rcp_f(1.0f + exp2_f(cst[r] * L2E2)), 1.0f);\
            h4_[r] = go * tc_;                                                 \
        }                                                                      \
        *reinterpret_cast<float4*>(out + ((size_t)b * T + (TCUR)) * 128 + u0) =\
            make_float4(h4_[0], h4_[1], h4_[2], h4_[3]);                       \
        u32x2 hw_;                                                             \
        hw_.x = cvtpk_bf16(h4_[0], h4_[1]);                                    \
        hw_.y = cvtpk_bf16(h4_[2], h4_[3]);                                    \
        *reinterpret_cast<u32x2*>(                                             \
            (char*)&WBUF[c][0] + ((u0 * 2) ^ SWZ(c))) = hw_;                   \
    }

__global__ __launch_bounds__(512) void k_lstm6(
    const _Float16* __restrict__ xp, const float* __restrict__ w_hh,
    float* __restrict__ out, int T)
{
    __shared__ __align__(16) unsigned short h_lds[2][16][128];  // bf16, 8 KB

    const int tid  = threadIdx.x;
    const int bk   = blockIdx.x;
    const int wv   = tid >> 6;
    const int lane = tid & 63;
    const int c    = lane & 15;
    const int q    = lane >> 4;
    const int u0   = wv * 16 + q * 4;
    const int b    = bk * 16 + c;

    // A-frags: scale[g] * W_hh[g*128 + wv*16 + c][ks*32+q*8 .. +8] (64 VGPR)
    bf16x8 afr[4][4];
#pragma unroll
    for (int g = 0; g < 4; ++g) {
        const float sc = (g == 2) ? L2E2 : -L2E;
        const float* wr = w_hh + (size_t)(g * 128 + wv * 16 + c) * 128;
#pragma unroll
        for (int ks = 0; ks < 4; ++ks) {
            float4 w0 = *reinterpret_cast<const float4*>(wr + ks * 32 + q * 8);
            float4 w1 = *reinterpret_cast<const float4*>(wr + ks * 32 + q * 8 + 4);
            w0.x *= sc; w0.y *= sc; w0.z *= sc; w0.w *= sc;
            w1.x *= sc; w1.y *= sc; w1.z *= sc; w1.w *= sc;
            afr[g][ks] = pack8(w0, w1);
        }
    }

    // init h(T) = 0
    {
        u32x2 z = {0u, 0u};
        *reinterpret_cast<u32x2*>(
            (char*)&h_lds[0][c][0] + ((u0 * 2) ^ SWZ(c))) = z;
    }
    f32x4 cst = {0.f, 0.f, 0.f, 0.f};

    const _Float16* xpb = xp + ((size_t)b * T) * 512 + (wv * 4 + q) * 16;
    f16x8 PA0 = *reinterpret_cast<const f16x8*>(xpb + (size_t)(T - 1) * 512);
    f16x8 PA1 = *reinterpret_cast<const f16x8*>(xpb + (size_t)(T - 1) * 512 + 8);
    f16x8 PB0 = *reinterpret_cast<const f16x8*>(xpb + (size_t)(T - 2) * 512);
    f16x8 PB1 = *reinterpret_cast<const f16x8*>(xpb + (size_t)(T - 2) * 512 + 8);
    __syncthreads();

    for (int t = T - 1; t > 0; t -= 2) {
        LSTM_BODY(t,     h_lds[0], h_lds[1], PA0, PA1, t - 2);
        __syncthreads();
        LSTM_BODY(t - 1, h_lds[1], h_lds[0], PB0, PB1, t - 3);
        __syncthreads();
    }
}

// ------------------- fallback LSTM (R9, K=256 interleaved) ------------------
__global__ __launch_bounds__(512) void k_lstm4(
    const float* __restrict__ feat, const float* __restrict__ w_ih,
    const float* __restrict__ w_hh, const float* __restrict__ b_ih,
    const float* __restrict__ b_hh, float* __restrict__ out, int T)
{
    __shared__ __align__(16) unsigned hx[2][16][128];
    __shared__ __align__(16) u32x4 wlds[8 * 2 * 8 * 64];

    const int tid  = threadIdx.x;
    const int bk   = blockIdx.x;
    const int wv   = tid >> 6;
    const int lane = tid & 63;
    const int c    = lane & 15;
    const int q    = lane >> 4;

    bf16x8 afr[2][8];
#pragma unroll
    for (int g = 0; g < 4; ++g) {
        const int row = g * 128 + wv * 16 + c;
#pragma unroll
        for (int ks = 0; ks < 8; ++ks) {
            const int m0 = ks * 16 + q * 4;
            float4 h4 = *reinterpret_cast<const float4*>(w_hh + (size_t)row * 128 + m0);
            float4 i4 = *reinterpret_cast<const float4*>(w_ih + (size_t)row * 128 + m0);
            u32x4 u;
            u.x = (bfr(i4.x) << 16) | bfr(h4.x);
            u.y = (bfr(i4.y) << 16) | bfr(h4.y);
            u.z = (bfr(i4.z) << 16) | bfr(h4.z);
            u.w = (bfr(i4.w) << 16) | bfr(h4.w);
            if (g < 2)
                afr[g][ks] = __builtin_bit_cast(bf16x8, u);
            else
                wlds[((wv * 2 + (g - 2)) * 8 + ks) * 64 + lane] = u;
        }
    }

    float bias[4][4];
#pragma unroll
    for (int g = 0; g < 4; ++g)
#pragma unroll
        for (int r = 0; r < 4; ++r) {
            const int j = wv * 16 + q * 4 + r;
            bias[g][r] = b_ih[g * 128 + j] + b_hh[g * 128 + j];
        }

    const size_t fbase = ((size_t)(bk * 16 + c)) * T;
    const int u0 = wv * 16 + q * 4;

    {
        float4 x0 = *reinterpret_cast<const float4*>(feat + (fbase + (T - 1)) * 128 + u0);
        u32x4 u;
        u.x = bfr(x0.x) << 16;
        u.y = bfr(x0.y) << 16;
        u.z = bfr(x0.z) << 16;
        u.w = bfr(x0.w) << 16;
        *reinterpret_cast<u32x4*>((char*)&hx[0][c][0] + ((u0 * 4) ^ SWZ(c))) = u;
    }
    f32x4 cst = {0.f, 0.f, 0.f, 0.f};
    __syncthreads();

    int cur = 0;
    for (int t = T - 1; t >= 0; --t) {
        const int tp = (t > 0) ? t - 1 : 0;
        float4 xpv = *reinterpret_cast<const float4*>(feat + (fbase + tp) * 128 + u0);

        f32x4 acc0 = {bias[0][0], bias[0][1], bias[0][2], bias[0][3]};
        f32x4 acc1 = {bias[1][0], bias[1][1], bias[1][2], bias[1][3]};
        f32x4 acc2 = {bias[2][0], bias[2][1], bias[2][2], bias[2][3]};
        f32x4 acc3 = {bias[3][0], bias[3][1], bias[3][2], bias[3][3]};

        const char* hrow = (const char*)&hx[cur][c][0];
        const u32x4* wp0 = &wlds[(wv * 2 + 0) * 8 * 64 + lane];
        const u32x4* wp1 = &wlds[(wv * 2 + 1) * 8 * 64 + lane];
#pragma unroll
        for (int ks = 0; ks < 8; ++ks) {
            u32x4 bq = *reinterpret_cast<const u32x4*>(
                hrow + ((ks * 64 + q * 16) ^ SWZ(c)));
            bf16x8 bf = __builtin_bit_cast(bf16x8, bq);
            acc0 = __builtin_amdgcn_mfma_f32_16x16x32_bf16(afr[0][ks], bf, acc0, 0, 0, 0);
            acc1 = __builtin_amdgcn_mfma_f32_16x16x32_bf16(afr[1][ks], bf, acc1, 0, 0, 0);
            bf16x8 a2 = __builtin_bit_cast(bf16x8, wp0[ks * 64]);
            acc2 = __builtin_amdgcn_mfma_f32_16x16x32_bf16(a2, bf, acc2, 0, 0, 0);
            bf16x8 a3 = __builtin_bit_cast(bf16x8, wp1[ks * 64]);
            acc3 = __builtin_amdgcn_mfma_f32_16x16x32_bf16(a3, bf, acc3, 0, 0, 0);
        }

        float h[4];
#pragma unroll
        for (int r = 0; r < 4; ++r) {
            float gi = sigf(acc0[r]);
            float gf = sigf(acc1[r]);
            float gg = tanhfast(acc2[r]);
            float go = sigf(acc3[r]);
            cst[r] = gf * cst[r] + gi * gg;
            h[r] = go * tanhfast(cst[r]);
        }
        *reinterpret_cast<float4*>(out + (fbase + t) * 128 + u0) =
            make_float4(h[0], h[1], h[2], h[3]);

        u32x4 u;
        u.x = (bfr(xpv.x) << 16) | bfr(h[0]);
        u.y = (bfr(xpv.y) << 16) | bfr(h[1]);
        u.z = (bfr(xpv.z) << 16) | bfr(h[2]);
        u.w = (bfr(xpv.w) << 16) | bfr(h[3]);
        *reinterpret_cast<u32x4*>((char*)&hx[cur ^ 1][c][0] + ((u0 * 4) ^ SWZ(c))) = u;

        cur ^= 1;
        __syncthreads();
    }
}

extern "C" void kernel_launch(void* const* d_in, const int* in_sizes, int n_in,
                              void* d_out, int out_size, void* d_ws, size_t ws_size,
                              hipStream_t stream)
{
    const float* x    = (const float*)d_in[0];
    const float* c1w  = (const float*)d_in[1];
    const float* bn1g = (const float*)d_in[2];
    const float* bn1b = (const float*)d_in[3];
    const float* bn1m = (const float*)d_in[4];
    const float* bn1v = (const float*)d_in[5];
    const float* c2w  = (const float*)d_in[6];
    const float* bn2g = (const float*)d_in[7];
    const float* bn2b = (const float*)d_in[8];
    const float* bn2m = (const float*)d_in[9];
    const float* bn2v = (const float*)d_in[10];
    const float* c3w  = (const float*)d_in[11];
    const float* bn3g = (const float*)d_in[12];
    const float* bn3b = (const float*)d_in[13];
    const float* bn3m = (const float*)d_in[14];
    const float* bn3v = (const float*)d_in[15];
    const float* w_ih = (const float*)d_in[16];
    const float* w_hh = (const float*)d_in[17];
    const float* b_ih = (const float*)d_in[18];
    const float* b_hh = (const float*)d_in[19];
    float* out = (float*)d_out;

    const int B = 64, T = 4096;
    char* ws = (char*)d_ws;
    const size_t sz_y1 = (size_t)B * 32 * T * 4;        //  32 MB
    const size_t sz_y2 = (size_t)B * 64 * T * 4;        //  64 MB
    const size_t sz_xp = (size_t)B * T * 512 * 2;       // 256 MB (f16)

    const bool fast = ws_size >= sz_y2 + sz_xp;         // 320 MB

    if (fast) {
        float* y1   = (float*)d_out;            // d_out scratch (dead later)
        float* y2   = (float*)ws;               // ws[0, 64MB)
        float* feat = (float*)d_out;            // d_out reused (y1 dead)
        _Float16* xp = (_Float16*)(ws + sz_y2); // ws[64, 320MB)

        k_conv1<<<dim3(T / 256, B), 256, 0, stream>>>(x, c1w, bn1g, bn1b, bn1m, bn1v, y1, B, T);
        k_conv2<<<dim3(T / 256, B), 256, 0, stream>>>(y1, c2w, bn2g, bn2b, bn2m, bn2v, y2, B, T);
        k_conv3<<<dim3(T / 128, B), 256, 0, stream>>>(y2, c3w, bn3g, bn3b, bn3m, bn3v, feat, B, T);
        k_xpre<<<dim3(T / 32, B), 256, 0, stream>>>(feat, w_ih, b_ih, b_hh, xp, T);
        k_lstm6<<<dim3(4), 512, 0, stream>>>(xp, w_hh, out, T);
    } else {
        float* y1   = (float*)ws;
        float* y2   = (float*)(ws + sz_y1);
        float* feat = (float*)(ws + sz_y1 + sz_y2);

        k_conv1<<<dim3(T / 256, B), 256, 0, stream>>>(x, c1w, bn1g, bn1b, bn1m, bn1v, y1, B, T);
        k_conv2<<<dim3(T / 256, B), 256, 0, stream>>>(y1, c2w, bn2g, bn2b, bn2m, bn2v, y2, B, T);
        k_conv3<<<dim3(T / 128, B), 256, 0, stream>>>(y2, c3w, bn3g, bn3b, bn3m, bn3v, feat, B, T);
        k_lstm4<<<dim3(4), 512, 0, stream>>>(feat, w_ih, w_hh, b_ih, b_hh, out, T);
    }
}

// Round 13
// 5831.376 us; speedup vs baseline: 3.1226x; 1.2576x over previous
//
#include <hip/hip_runtime.h>
#include <cstdint>
#include <cstddef>

#define BN_EPS 1e-5f
#define L2E   1.4426950408889634f
#define L2E2  2.8853900817779268f

typedef __attribute__((ext_vector_type(8))) short  bf16x8;
typedef __attribute__((ext_vector_type(4))) float  f32x4;
typedef __attribute__((ext_vector_type(4))) unsigned u32x4;
typedef __attribute__((ext_vector_type(2))) unsigned u32x2;
typedef __attribute__((ext_vector_type(8))) _Float16 f16x8;
typedef __attribute__((ext_vector_type(4))) _Float16 f16x4;

__device__ __forceinline__ float sigf(float x) {
    return 1.0f / (1.0f + __expf(-x));
}
__device__ __forceinline__ float tanhfast(float x) {
    return 2.0f / (1.0f + __expf(-2.0f * x)) - 1.0f;
}
__device__ __forceinline__ unsigned bfr(float x) {  // f32 -> bf16 bits (RNE)
    unsigned u = __float_as_uint(x);
    return (u + 0x7fffu + ((u >> 16) & 1u)) >> 16;
}
__device__ __forceinline__ bf16x8 pack8(float4 a, float4 b) {  // ascending k
    u32x4 u;
    u.x = (bfr(a.y) << 16) | bfr(a.x);
    u.y = (bfr(a.w) << 16) | bfr(a.z);
    u.z = (bfr(b.y) << 16) | bfr(b.x);
    u.w = (bfr(b.w) << 16) | bfr(b.z);
    return __builtin_bit_cast(bf16x8, u);
}
// fast HW ops via INTRINSICS (R11: raw asm v_rcp/v_exp -> stale-reg hazard)
__device__ __forceinline__ float rcp_f(float x) {
    return __builtin_amdgcn_rcpf(x);
}
__device__ __forceinline__ float exp2_f(float x) {
    return __builtin_amdgcn_exp2f(x);
}
__device__ __forceinline__ unsigned cvtpk_bf16(float lo, float hi) {
    unsigned r; asm("v_cvt_pk_bf16_f32 %0, %1, %2" : "=v"(r) : "v"(lo), "v"(hi));
    return r;
}

// Counted barrier: drain LDS only (lgkmcnt), leave global loads/stores in
// flight across the barrier. __syncthreads() would emit s_waitcnt vmcnt(0)
// and expose HBM latency every step (R12's hidden ~1800 cyc/step).
#define LBAR()                                                   \
    do {                                                         \
        asm volatile("s_waitcnt lgkmcnt(0)" ::: "memory");       \
        __builtin_amdgcn_s_barrier();                            \
        asm volatile("" ::: "memory");                           \
    } while (0)

// ---------------- conv1 + BN + ReLU : x[B,T,9] -> y1[B,32,T] ----------------
__global__ __launch_bounds__(256) void k_conv1(
    const float* __restrict__ x, const float* __restrict__ w,
    const float* __restrict__ g, const float* __restrict__ bb,
    const float* __restrict__ m, const float* __restrict__ v,
    float* __restrict__ y1, int B, int T)
{
    const int TT = 256;
    __shared__ float xs[(TT + 6) * 9];
    const int b = blockIdx.y;
    const int t0 = blockIdx.x * TT;
    const int tid = threadIdx.x;

    for (int idx = tid; idx < (TT + 6) * 9; idx += 256) {
        int row = idx / 9, col = idx - row * 9;
        int tg = t0 - 3 + row;
        xs[idx] = (tg >= 0 && tg < T) ? x[((size_t)b * T + tg) * 9 + col] : 0.0f;
    }
    __syncthreads();

    float xv[63];
#pragma unroll
    for (int k = 0; k < 7; ++k)
#pragma unroll
        for (int ci = 0; ci < 9; ++ci)
            xv[k * 9 + ci] = xs[(tid + k) * 9 + ci];

    const int t = t0 + tid;
    for (int co = 0; co < 32; ++co) {
        float acc = 0.0f;
#pragma unroll
        for (int ci = 0; ci < 9; ++ci)
#pragma unroll
            for (int k = 0; k < 7; ++k)
                acc += xv[k * 9 + ci] * w[(co * 9 + ci) * 7 + k];
        float sc = g[co] / sqrtf(v[co] + BN_EPS);
        float bf = bb[co] - m[co] * sc;
        float o = acc * sc + bf;
        y1[((size_t)b * 32 + co) * T + t] = o > 0.0f ? o : 0.0f;
    }
}

// ---------------- conv2 + BN + ReLU : y1[B,32,T] -> y2[B,64,T] --------------
__global__ __launch_bounds__(256) void k_conv2(
    const float* __restrict__ y1, const float* __restrict__ w,
    const float* __restrict__ g, const float* __restrict__ bb,
    const float* __restrict__ m, const float* __restrict__ v,
    float* __restrict__ y2, int B, int T)
{
    const int TT = 256;
    __shared__ float ys[32 * (TT + 6)];
    const int b = blockIdx.y;
    const int t0 = blockIdx.x * TT;
    const int tid = threadIdx.x;

    for (int idx = tid; idx < 32 * (TT + 6); idx += 256) {
        int ci = idx / (TT + 6), i = idx - ci * (TT + 6);
        int tg = t0 - 3 + i;
        ys[idx] = (tg >= 0 && tg < T) ? y1[((size_t)b * 32 + ci) * T + tg] : 0.0f;
    }
    __syncthreads();

    float acc[64];
#pragma unroll
    for (int co = 0; co < 64; ++co) acc[co] = 0.0f;

    for (int ci = 0; ci < 32; ++ci) {
        float yw[7];
#pragma unroll
        for (int k = 0; k < 7; ++k) yw[k] = ys[ci * (TT + 6) + tid + k];
#pragma unroll
        for (int co = 0; co < 64; ++co)
#pragma unroll
            for (int k = 0; k < 7; ++k)
                acc[co] += yw[k] * w[(co * 32 + ci) * 7 + k];
    }

    const int t = t0 + tid;
    for (int co = 0; co < 64; ++co) {
        float sc = g[co] / sqrtf(v[co] + BN_EPS);
        float bf = bb[co] - m[co] * sc;
        float o = acc[co] * sc + bf;
        y2[((size_t)b * 64 + co) * T + t] = o > 0.0f ? o : 0.0f;
    }
}

// ------------- conv3 + BN + ReLU : y2[B,64,T] -> feat[B,T,128] --------------
__global__ __launch_bounds__(256) void k_conv3(
    const float* __restrict__ y2, const float* __restrict__ w,
    const float* __restrict__ g, const float* __restrict__ bb,
    const float* __restrict__ m, const float* __restrict__ v,
    float* __restrict__ feat, int B, int T)
{
    const int TT = 128;
    __shared__ float ys[64 * (TT + 6)];
    const int b = blockIdx.y;
    const int t0 = blockIdx.x * TT;
    const int tid = threadIdx.x;
    const int tl = tid & 127;
    const int half = __builtin_amdgcn_readfirstlane(tid >> 7);  // wave-uniform

    for (int idx = tid; idx < 64 * (TT + 6); idx += 256) {
        int ci = idx / (TT + 6), i = idx - ci * (TT + 6);
        int tg = t0 - 3 + i;
        ys[idx] = (tg >= 0 && tg < T) ? y2[((size_t)b * 64 + ci) * T + tg] : 0.0f;
    }
    __syncthreads();

    float acc[64];
#pragma unroll
    for (int q = 0; q < 64; ++q) acc[q] = 0.0f;

    for (int ci = 0; ci < 64; ++ci) {
        float yw[7];
#pragma unroll
        for (int k = 0; k < 7; ++k) yw[k] = ys[ci * (TT + 6) + tl + k];
#pragma unroll
        for (int q = 0; q < 64; ++q)
#pragma unroll
            for (int k = 0; k < 7; ++k)
                acc[q] += yw[k] * w[((half * 64 + q) * 64 + ci) * 7 + k];
    }

    const int t = t0 + tl;
    for (int q = 0; q < 64; ++q) {
        int co = half * 64 + q;
        float sc = g[co] / sqrtf(v[co] + BN_EPS);
        float bf = bb[co] - m[co] * sc;
        float o = acc[q] * sc + bf;
        feat[((size_t)b * T + t) * 128 + co] = o > 0.0f ? o : 0.0f;
    }
}

// ----------- x-projection GEMM: xp = scale_g*(W_ih·x + b) (f16) -------------
__global__ __launch_bounds__(256) void k_xpre(
    const float* __restrict__ feat, const float* __restrict__ w_ih,
    const float* __restrict__ b_ih, const float* __restrict__ b_hh,
    _Float16* __restrict__ xp, int T)
{
    const int b   = blockIdx.y;
    const int t0  = blockIdx.x * 32;
    const int tid = threadIdx.x;
    const int wv2 = tid >> 6;      // gate g
    const int lane = tid & 63;
    const int c2 = lane & 15;
    const int q2 = lane >> 4;
    const float sc = (wv2 == 2) ? L2E2 : -L2E;

    bf16x8 btile[2][4];
#pragma unroll
    for (int tc = 0; tc < 2; ++tc) {
        const float* xrow = feat + ((size_t)b * T + t0 + tc * 16 + c2) * 128;
#pragma unroll
        for (int ks = 0; ks < 4; ++ks) {
            float4 x0 = *reinterpret_cast<const float4*>(xrow + ks * 32 + q2 * 8);
            float4 x1 = *reinterpret_cast<const float4*>(xrow + ks * 32 + q2 * 8 + 4);
            btile[tc][ks] = pack8(x0, x1);
        }
    }

#pragma unroll
    for (int rt = 0; rt < 8; ++rt) {
        const int row = wv2 * 128 + rt * 16 + c2;
        bf16x8 a[4];
#pragma unroll
        for (int ks = 0; ks < 4; ++ks) {
            float4 w0 = *reinterpret_cast<const float4*>(w_ih + (size_t)row * 128 + ks * 32 + q2 * 8);
            float4 w1 = *reinterpret_cast<const float4*>(w_ih + (size_t)row * 128 + ks * 32 + q2 * 8 + 4);
            w0.x *= sc; w0.y *= sc; w0.z *= sc; w0.w *= sc;
            w1.x *= sc; w1.y *= sc; w1.z *= sc; w1.w *= sc;
            a[ks] = pack8(w0, w1);
        }
        const int gr0 = wv2 * 128 + rt * 16 + q2 * 4;
        float4 bi = *reinterpret_cast<const float4*>(b_ih + gr0);
        float4 bh = *reinterpret_cast<const float4*>(b_hh + gr0);
        f32x4 bias = {(bi.x + bh.x) * sc, (bi.y + bh.y) * sc,
                      (bi.z + bh.z) * sc, (bi.w + bh.w) * sc};

#pragma unroll
        for (int tc = 0; tc < 2; ++tc) {
            f32x4 acc = bias;
#pragma unroll
            for (int ks = 0; ks < 4; ++ks)
                acc = __builtin_amdgcn_mfma_f32_16x16x32_bf16(a[ks], btile[tc][ks], acc, 0, 0, 0);
            const int t = t0 + tc * 16 + c2;
            f16x4 hv = {(_Float16)acc[0], (_Float16)acc[1],
                        (_Float16)acc[2], (_Float16)acc[3]};
            *reinterpret_cast<f16x4*>(
                xp + ((size_t)b * T + t) * 512 + (rt * 4 + q2) * 16 + wv2 * 4) = hv;
        }
    }
}

// --------------------- reversed-time LSTM (MFMA, K=128) ---------------------
// 8 blocks x 8 batches (cols 8-15 masked: hx rows stay 0, out stores guarded,
// xp addrs clamped -> per-CU xp/out traffic halved vs R12's 4x16).
// Counted barrier (LBAR) keeps global loads/stores in flight across steps.
#define SWZ(b) (((b) & 7) << 4)

#define LSTM_BODY(TCUR, RBUF, WBUF, Q0, Q1, PFT)                              \
    {                                                                          \
        f32x4 acc0 = {(float)Q0[0], (float)Q0[1], (float)Q0[2], (float)Q0[3]}; \
        f32x4 acc1 = {(float)Q0[4], (float)Q0[5], (float)Q0[6], (float)Q0[7]}; \
        f32x4 acc2 = {(float)Q1[0], (float)Q1[1], (float)Q1[2], (float)Q1[3]}; \
        f32x4 acc3 = {(float)Q1[4], (float)Q1[5], (float)Q1[6], (float)Q1[7]}; \
        const int pt_ = ((PFT) >= 0) ? (PFT) : 0;                              \
        Q0 = *reinterpret_cast<const f16x8*>(xpb + (size_t)pt_ * 512);         \
        Q1 = *reinterpret_cast<const f16x8*>(xpb + (size_t)pt_ * 512 + 8);     \
        const char* hrow_ = (const char*)&RBUF[c][0];                          \
        _Pragma("unroll")                                                      \
        for (int ks = 0; ks < 4; ++ks) {                                       \
            u32x4 bq = *reinterpret_cast<const u32x4*>(                        \
                hrow_ + ((ks * 64 + q * 16) ^ SWZ(c)));                        \
            bf16x8 bf = __builtin_bit_cast(bf16x8, bq);                        \
            acc0 = __builtin_amdgcn_mfma_f32_16x16x32_bf16(afr[0][ks], bf, acc0, 0, 0, 0); \
            acc1 = __builtin_amdgcn_mfma_f32_16x16x32_bf16(afr[1][ks], bf, acc1, 0, 0, 0); \
            acc2 = __builtin_amdgcn_mfma_f32_16x16x32_bf16(afr[2][ks], bf, acc2, 0, 0, 0); \
            acc3 = __builtin_amdgcn_mfma_f32_16x16x32_bf16(afr[3][ks], bf, acc3, 0, 0, 0); \
        }                                                                      \
        float h4_[4];                                                          \
        _Pragma("unroll")                                                      \
        for (int r = 0; r < 4; ++r) {                                          \
            float gi = rcp_f(1.0f + exp2_f(acc0[r]));                          \
            float gf = rcp_f(1.0f + exp2_f(acc1[r]));                          \
            float gg = fmaf(-2.0f, rcp_f(1.0f + exp2_f(acc2[r])), 1.0f);       \
            float go = rcp_f(1.0f + exp2_f(acc3[r]));                          \
            cst[r] = fmaf(gf, cst[r], gi * gg);                                \
            float tc_ = fmaf(-2.0f, rcp_f(1.0f + exp2_f(cst[r] * L2E2)), 1.0f);\
            h4_[r] = go * tc_;                                                 \
        }                                                                      \
        if (valid) {                                                           \
            *reinterpret_cast<float4*>(out + ((size_t)b * T + (TCUR)) * 128 + u0) = \
                make_float4(h4_[0], h4_[1], h4_[2], h4_[3]);                   \
            u32x2 hw_;                                                         \
            hw_.x = cvtpk_bf16(h4_[0], h4_[1]);                                \
            hw_.y = cvtpk_bf16(h4_[2], h4_[3]);                                \
            *reinterpret_cast<u32x2*>(                                         \
                (char*)&WBUF[c][0] + ((u0 * 2) ^ SWZ(c))) = hw_;               \
        }                                                                      \
    }

__global__ __launch_bounds__(512) void k_lstm7(
    const _Float16* __restrict__ xp, const float* __restrict__ w_hh,
    float* __restrict__ out, int T)
{
    __shared__ __align__(16) unsigned short h_lds[2][16][128];  // bf16, 8 KB

    const int tid  = threadIdx.x;
    const int bk   = blockIdx.x;          // batches [bk*8, bk*8+8)
    const int wv   = tid >> 6;
    const int lane = tid & 63;
    const int c    = lane & 15;
    const int q    = lane >> 4;
    const int u0   = wv * 16 + q * 4;
    const bool valid = (c < 8);
    const int b    = bk * 8 + (c & 7);    // clamped for invalid lanes

    // A-frags: scale[g] * W_hh[g*128 + wv*16 + c][ks*32+q*8 .. +8] (AGPR-able)
    bf16x8 afr[4][4];
#pragma unroll
    for (int g = 0; g < 4; ++g) {
        const float sc = (g == 2) ? L2E2 : -L2E;
        const float* wr = w_hh + (size_t)(g * 128 + wv * 16 + c) * 128;
#pragma unroll
        for (int ks = 0; ks < 4; ++ks) {
            float4 w0 = *reinterpret_cast<const float4*>(wr + ks * 32 + q * 8);
            float4 w1 = *reinterpret_cast<const float4*>(wr + ks * 32 + q * 8 + 4);
            w0.x *= sc; w0.y *= sc; w0.z *= sc; w0.w *= sc;
            w1.x *= sc; w1.y *= sc; w1.z *= sc; w1.w *= sc;
            afr[g][ks] = pack8(w0, w1);
        }
    }

    // init h(T) = 0 for BOTH buffers, ALL 16 cols (cols 8-15 stay 0 forever)
    {
        u32x2 z = {0u, 0u};
        *reinterpret_cast<u32x2*>((char*)&h_lds[0][c][0] + ((u0 * 2) ^ SWZ(c))) = z;
        *reinterpret_cast<u32x2*>((char*)&h_lds[1][c][0] + ((u0 * 2) ^ SWZ(c))) = z;
    }
    f32x4 cst = {0.f, 0.f, 0.f, 0.f};

    const _Float16* xpb = xp + ((size_t)b * T) * 512 + (wv * 4 + q) * 16;
    f16x8 PA0 = *reinterpret_cast<const f16x8*>(xpb + (size_t)(T - 1) * 512);
    f16x8 PA1 = *reinterpret_cast<const f16x8*>(xpb + (size_t)(T - 1) * 512 + 8);
    f16x8 PB0 = *reinterpret_cast<const f16x8*>(xpb + (size_t)(T - 2) * 512);
    f16x8 PB1 = *reinterpret_cast<const f16x8*>(xpb + (size_t)(T - 2) * 512 + 8);
    __syncthreads();

    for (int t = T - 1; t > 0; t -= 2) {
        LSTM_BODY(t,     h_lds[0], h_lds[1], PA0, PA1, t - 2);
        LBAR();
        LSTM_BODY(t - 1, h_lds[1], h_lds[0], PB0, PB1, t - 3);
        LBAR();
    }
}

// ------------------- fallback LSTM (R9, K=256 interleaved) ------------------
__global__ __launch_bounds__(512) void k_lstm4(
    const float* __restrict__ feat, const float* __restrict__ w_ih,
    const float* __restrict__ w_hh, const float* __restrict__ b_ih,
    const float* __restrict__ b_hh, float* __restrict__ out, int T)
{
    __shared__ __align__(16) unsigned hx[2][16][128];
    __shared__ __align__(16) u32x4 wlds[8 * 2 * 8 * 64];

    const int tid  = threadIdx.x;
    const int bk   = blockIdx.x;
    const int wv   = tid >> 6;
    const int lane = tid & 63;
    const int c    = lane & 15;
    const int q    = lane >> 4;

    bf16x8 afr[2][8];
#pragma unroll
    for (int g = 0; g < 4; ++g) {
        const int row = g * 128 + wv * 16 + c;
#pragma unroll
        for (int ks = 0; ks < 8; ++ks) {
            const int m0 = ks * 16 + q * 4;
            float4 h4 = *reinterpret_cast<const float4*>(w_hh + (size_t)row * 128 + m0);
            float4 i4 = *reinterpret_cast<const float4*>(w_ih + (size_t)row * 128 + m0);
            u32x4 u;
            u.x = (bfr(i4.x) << 16) | bfr(h4.x);
            u.y = (bfr(i4.y) << 16) | bfr(h4.y);
            u.z = (bfr(i4.z) << 16) | bfr(h4.z);
            u.w = (bfr(i4.w) << 16) | bfr(h4.w);
            if (g < 2)
                afr[g][ks] = __builtin_bit_cast(bf16x8, u);
            else
                wlds[((wv * 2 + (g - 2)) * 8 + ks) * 64 + lane] = u;
        }
    }

    float bias[4][4];
#pragma unroll
    for (int g = 0; g < 4; ++g)
#pragma unroll
        for (int r = 0; r < 4; ++r) {
            const int j = wv * 16 + q * 4 + r;
            bias[g][r] = b_ih[g * 128 + j] + b_hh[g * 128 + j];
        }

    const size_t fbase = ((size_t)(bk * 16 + c)) * T;
    const int u0 = wv * 16 + q * 4;

    {
        float4 x0 = *reinterpret_cast<const float4*>(feat + (fbase + (T - 1)) * 128 + u0);
        u32x4 u;
        u.x = bfr(x0.x) << 16;
        u.y = bfr(x0.y) << 16;
        u.z = bfr(x0.z) << 16;
        u.w = bfr(x0.w) << 16;
        *reinterpret_cast<u32x4*>((char*)&hx[0][c][0] + ((u0 * 4) ^ SWZ(c))) = u;
    }
    f32x4 cst = {0.f, 0.f, 0.f, 0.f};
    __syncthreads();

    int cur = 0;
    for (int t = T - 1; t >= 0; --t) {
        const int tp = (t > 0) ? t - 1 : 0;
        float4 xpv = *reinterpret_cast<const float4*>(feat + (fbase + tp) * 128 + u0);

        f32x4 acc0 = {bias[0][0], bias[0][1], bias[0][2], bias[0][3]};
        f32x4 acc1 = {bias[1][0], bias[1][1], bias[1][2], bias[1][3]};
        f32x4 acc2 = {bias[2][0], bias[2][1], bias[2][2], bias[2][3]};
        f32x4 acc3 = {bias[3][0], bias[3][1], bias[3][2], bias[3][3]};

        const char* hrow = (const char*)&hx[cur][c][0];
        const u32x4* wp0 = &wlds[(wv * 2 + 0) * 8 * 64 + lane];
        const u32x4* wp1 = &wlds[(wv * 2 + 1) * 8 * 64 + lane];
#pragma unroll
        for (int ks = 0; ks < 8; ++ks) {
            u32x4 bq = *reinterpret_cast<const u32x4*>(
                hrow + ((ks * 64 + q * 16) ^ SWZ(c)));
            bf16x8 bf = __builtin_bit_cast(bf16x8, bq);
            acc0 = __builtin_amdgcn_mfma_f32_16x16x32_bf16(afr[0][ks], bf, acc0, 0, 0, 0);
            acc1 = __builtin_amdgcn_mfma_f32_16x16x32_bf16(afr[1][ks], bf, acc1, 0, 0, 0);
            bf16x8 a2 = __builtin_bit_cast(bf16x8, wp0[ks * 64]);
            acc2 = __builtin_amdgcn_mfma_f32_16x16x32_bf16(a2, bf, acc2, 0, 0, 0);
            bf16x8 a3 = __builtin_bit_cast(bf16x8, wp1[ks * 64]);
            acc3 = __builtin_amdgcn_mfma_f32_16x16x32_bf16(a3, bf, acc3, 0, 0, 0);
        }

        float h[4];
#pragma unroll
        for (int r = 0; r < 4; ++r) {
            float gi = sigf(acc0[r]);
            float gf = sigf(acc1[r]);
            float gg = tanhfast(acc2[r]);
            float go = sigf(acc3[r]);
            cst[r] = gf * cst[r] + gi * gg;
            h[r] = go * tanhfast(cst[r]);
        }
        *reinterpret_cast<float4*>(out + (fbase + t) * 128 + u0) =
            make_float4(h[0], h[1], h[2], h[3]);

        u32x4 u;
        u.x = (bfr(xpv.x) << 16) | bfr(h[0]);
        u.y = (bfr(xpv.y) << 16) | bfr(h[1]);
        u.z = (bfr(xpv.z) << 16) | bfr(h[2]);
        u.w = (bfr(xpv.w) << 16) | bfr(h[3]);
        *reinterpret_cast<u32x4*>((char*)&hx[cur ^ 1][c][0] + ((u0 * 4) ^ SWZ(c))) = u;

        cur ^= 1;
        __syncthreads();
    }
}

extern "C" void kernel_launch(void* const* d_in, const int* in_sizes, int n_in,
                              void* d_out, int out_size, void* d_ws, size_t ws_size,
                              hipStream_t stream)
{
    const float* x    = (const float*)d_in[0];
    const float* c1w  = (const float*)d_in[1];
    const float* bn1g = (const float*)d_in[2];
    const float* bn1b = (const float*)d_in[3];
    const float* bn1m = (const float*)d_in[4];
    const float* bn1v = (const float*)d_in[5];
    const float* c2w  = (const float*)d_in[6];
    const float* bn2g = (const float*)d_in[7];
    const float* bn2b = (const float*)d_in[8];
    const float* bn2m = (const float*)d_in[9];
    const float* bn2v = (const float*)d_in[10];
    const float* c3w  = (const float*)d_in[11];
    const float* bn3g = (const float*)d_in[12];
    const float* bn3b = (const float*)d_in[13];
    const float* bn3m = (const float*)d_in[14];
    const float* bn3v = (const float*)d_in[15];
    const float* w_ih = (const float*)d_in[16];
    const float* w_hh = (const float*)d_in[17];
    const float* b_ih = (const float*)d_in[18];
    const float* b_hh = (const float*)d_in[19];
    float* out = (float*)d_out;

    const int B = 64, T = 4096;
    char* ws = (char*)d_ws;
    const size_t sz_y1 = (size_t)B * 32 * T * 4;        //  32 MB
    const size_t sz_y2 = (size_t)B * 64 * T * 4;        //  64 MB
    const size_t sz_xp = (size_t)B * T * 512 * 2;       // 256 MB (f16)

    const bool fast = ws_size >= sz_y2 + sz_xp;         // 320 MB

    if (fast) {
        float* y1   = (float*)d_out;            // d_out scratch (dead later)
        float* y2   = (float*)ws;               // ws[0, 64MB)
        float* feat = (float*)d_out;            // d_out reused (y1 dead)
        _Float16* xp = (_Float16*)(ws + sz_y2); // ws[64, 320MB)

        k_conv1<<<dim3(T / 256, B), 256, 0, stream>>>(x, c1w, bn1g, bn1b, bn1m, bn1v, y1, B, T);
        k_conv2<<<dim3(T / 256, B), 256, 0, stream>>>(y1, c2w, bn2g, bn2b, bn2m, bn2v, y2, B, T);
        k_conv3<<<dim3(T / 128, B), 256, 0, stream>>>(y2, c3w, bn3g, bn3b, bn3m, bn3v, feat, B, T);
        k_xpre<<<dim3(T / 32, B), 256, 0, stream>>>(feat, w_ih, b_ih, b_hh, xp, T);
        k_lstm7<<<dim3(8), 512, 0, stream>>>(xp, w_hh, out, T);
    } else {
        float* y1   = (float*)ws;
        float* y2   = (float*)(ws + sz_y1);
        float* feat = (float*)(ws + sz_y1 + sz_y2);

        k_conv1<<<dim3(T / 256, B), 256, 0, stream>>>(x, c1w, bn1g, bn1b, bn1m, bn1v, y1, B, T);
        k_conv2<<<dim3(T / 256, B), 256, 0, stream>>>(y1, c2w, bn2g, bn2b, bn2m, bn2v, y2, B, T);
        k_conv3<<<dim3(T / 128, B), 256, 0, stream>>>(y2, c3w, bn3g, bn3b, bn3m, bn3v, feat, B, T);
        k_lstm4<<<dim3(4), 512, 0, stream>>>(feat, w_ih, w_hh, b_ih, b_hh, out, T);
    }
}

// Round 14
// 4300.274 us; speedup vs baseline: 4.2344x; 1.3560x over previous
//
#include <hip/hip_runtime.h>
#include <cstdint>
#include <cstddef>

#define BN_EPS 1e-5f
#define L2E   1.4426950408889634f
#define L2E2  2.8853900817779268f

typedef __attribute__((ext_vector_type(8))) short  bf16x8;
typedef __attribute__((ext_vector_type(4))) float  f32x4;
typedef __attribute__((ext_vector_type(4))) unsigned u32x4;
typedef __attribute__((ext_vector_type(2))) unsigned u32x2;
typedef __attribute__((ext_vector_type(8))) _Float16 f16x8;
typedef __attribute__((ext_vector_type(4))) _Float16 f16x4;

__device__ __forceinline__ float sigf(float x) {
    return 1.0f / (1.0f + __expf(-x));
}
__device__ __forceinline__ float tanhfast(float x) {
    return 2.0f / (1.0f + __expf(-2.0f * x)) - 1.0f;
}
__device__ __forceinline__ unsigned bfr(float x) {  // f32 -> bf16 bits (RNE)
    unsigned u = __float_as_uint(x);
    return (u + 0x7fffu + ((u >> 16) & 1u)) >> 16;
}
__device__ __forceinline__ bf16x8 pack8(float4 a, float4 b) {  // ascending k
    u32x4 u;
    u.x = (bfr(a.y) << 16) | bfr(a.x);
    u.y = (bfr(a.w) << 16) | bfr(a.z);
    u.z = (bfr(b.y) << 16) | bfr(b.x);
    u.w = (bfr(b.w) << 16) | bfr(b.z);
    return __builtin_bit_cast(bf16x8, u);
}
__device__ __forceinline__ float rcp_f(float x) {
    return __builtin_amdgcn_rcpf(x);
}
__device__ __forceinline__ float exp2_f(float x) {
    return __builtin_amdgcn_exp2f(x);
}
__device__ __forceinline__ unsigned cvtpk_bf16(float lo, float hi) {
    unsigned r; asm("v_cvt_pk_bf16_f32 %0, %1, %2" : "=v"(r) : "v"(lo), "v"(hi));
    return r;
}

// LDS-only barrier (R13): global loads/stores stay in flight.
#define LBAR()                                                   \
    do {                                                         \
        asm volatile("s_waitcnt lgkmcnt(0)" ::: "memory");       \
        __builtin_amdgcn_s_barrier();                            \
        asm volatile("" ::: "memory");                           \
    } while (0)

// ---------------- conv1 + BN + ReLU : x[B,T,9] -> y1[B,32,T] ----------------
__global__ __launch_bounds__(256) void k_conv1(
    const float* __restrict__ x, const float* __restrict__ w,
    const float* __restrict__ g, const float* __restrict__ bb,
    const float* __restrict__ m, const float* __restrict__ v,
    float* __restrict__ y1, int B, int T)
{
    const int TT = 256;
    __shared__ float xs[(TT + 6) * 9];
    const int b = blockIdx.y;
    const int t0 = blockIdx.x * TT;
    const int tid = threadIdx.x;

    for (int idx = tid; idx < (TT + 6) * 9; idx += 256) {
        int row = idx / 9, col = idx - row * 9;
        int tg = t0 - 3 + row;
        xs[idx] = (tg >= 0 && tg < T) ? x[((size_t)b * T + tg) * 9 + col] : 0.0f;
    }
    __syncthreads();

    float xv[63];
#pragma unroll
    for (int k = 0; k < 7; ++k)
#pragma unroll
        for (int ci = 0; ci < 9; ++ci)
            xv[k * 9 + ci] = xs[(tid + k) * 9 + ci];

    const int t = t0 + tid;
    for (int co = 0; co < 32; ++co) {
        float acc = 0.0f;
#pragma unroll
        for (int ci = 0; ci < 9; ++ci)
#pragma unroll
            for (int k = 0; k < 7; ++k)
                acc += xv[k * 9 + ci] * w[(co * 9 + ci) * 7 + k];
        float sc = g[co] / sqrtf(v[co] + BN_EPS);
        float bf = bb[co] - m[co] * sc;
        float o = acc * sc + bf;
        y1[((size_t)b * 32 + co) * T + t] = o > 0.0f ? o : 0.0f;
    }
}

// ------ conv2 + BN + ReLU : y1[B,32,T] -> y2t[B,T,64]  (t-major output) -----
__global__ __launch_bounds__(256) void k_conv2(
    const float* __restrict__ y1, const float* __restrict__ w,
    const float* __restrict__ g, const float* __restrict__ bb,
    const float* __restrict__ m, const float* __restrict__ v,
    float* __restrict__ y2t, int B, int T)
{
    const int TT = 256;
    __shared__ float ys[32 * (TT + 6)];
    const int b = blockIdx.y;
    const int t0 = blockIdx.x * TT;
    const int tid = threadIdx.x;

    for (int idx = tid; idx < 32 * (TT + 6); idx += 256) {
        int ci = idx / (TT + 6), i = idx - ci * (TT + 6);
        int tg = t0 - 3 + i;
        ys[idx] = (tg >= 0 && tg < T) ? y1[((size_t)b * 32 + ci) * T + tg] : 0.0f;
    }
    __syncthreads();

    float acc[64];
#pragma unroll
    for (int co = 0; co < 64; ++co) acc[co] = 0.0f;

    for (int ci = 0; ci < 32; ++ci) {
        float yw[7];
#pragma unroll
        for (int k = 0; k < 7; ++k) yw[k] = ys[ci * (TT + 6) + tid + k];
#pragma unroll
        for (int co = 0; co < 64; ++co)
#pragma unroll
            for (int k = 0; k < 7; ++k)
                acc[co] += yw[k] * w[(co * 32 + ci) * 7 + k];
    }

    const int t = t0 + tid;
    float* orow = y2t + ((size_t)b * T + t) * 64;
    for (int co = 0; co < 64; co += 4) {
        float4 o;
        float s0 = g[co+0] / sqrtf(v[co+0] + BN_EPS);
        float s1 = g[co+1] / sqrtf(v[co+1] + BN_EPS);
        float s2 = g[co+2] / sqrtf(v[co+2] + BN_EPS);
        float s3 = g[co+3] / sqrtf(v[co+3] + BN_EPS);
        o.x = acc[co+0] * s0 + (bb[co+0] - m[co+0] * s0);
        o.y = acc[co+1] * s1 + (bb[co+1] - m[co+1] * s1);
        o.z = acc[co+2] * s2 + (bb[co+2] - m[co+2] * s2);
        o.w = acc[co+3] * s3 + (bb[co+3] - m[co+3] * s3);
        o.x = o.x > 0.f ? o.x : 0.f;
        o.y = o.y > 0.f ? o.y : 0.f;
        o.z = o.z > 0.f ? o.z : 0.f;
        o.w = o.w > 0.f ? o.w : 0.f;
        *reinterpret_cast<float4*>(orow + co) = o;
    }
}

// ---- pack conv3 weights -> bf16 frag order, BN scale folded ----------------
// A[co][k'=kk*64+ci] = w3[co][ci][kk] * sc3[co]; frag (rt,ks,lane): lane(c,q)
// holds A[rt*16+c][32ks+8q+j], j=0..7 (kk=ks>>1, ci=(ks&1)*32+8q+j). 7168 tuples.
__global__ __launch_bounds__(256) void k_pack_w3(
    const float* __restrict__ w3, const float* __restrict__ g,
    const float* __restrict__ v, unsigned* __restrict__ apk)
{
    int tu = blockIdx.x * 256 + threadIdx.x;
    if (tu >= 8 * 14 * 64) return;
    int lane = tu & 63, ks = (tu >> 6) % 14, rt = tu / (14 * 64);
    int c = lane & 15, q = lane >> 4;
    int co = rt * 16 + c, kk = ks >> 1, ci0 = (ks & 1) * 32 + q * 8;
    float sc = g[co] / sqrtf(v[co] + BN_EPS);
    float4 a, b;
    a.x = w3[(co * 64 + ci0 + 0) * 7 + kk] * sc;
    a.y = w3[(co * 64 + ci0 + 1) * 7 + kk] * sc;
    a.z = w3[(co * 64 + ci0 + 2) * 7 + kk] * sc;
    a.w = w3[(co * 64 + ci0 + 3) * 7 + kk] * sc;
    b.x = w3[(co * 64 + ci0 + 4) * 7 + kk] * sc;
    b.y = w3[(co * 64 + ci0 + 5) * 7 + kk] * sc;
    b.z = w3[(co * 64 + ci0 + 6) * 7 + kk] * sc;
    b.w = w3[(co * 64 + ci0 + 7) * 7 + kk] * sc;
    bf16x8 p = pack8(a, b);
    *reinterpret_cast<u32x4*>(apk + (size_t)tu * 4) = __builtin_bit_cast(u32x4, p);
}

// ---- pack W_ih -> bf16 frag order, gate exp2-scales folded. 8192 tuples ----
__global__ __launch_bounds__(256) void k_pack_wih(
    const float* __restrict__ w_ih, unsigned* __restrict__ wpk)
{
    int tu = blockIdx.x * 256 + threadIdx.x;
    if (tu >= 4 * 8 * 4 * 64) return;
    int lane = tu & 63, ks = (tu >> 6) & 3, rt = (tu >> 8) & 7, gg = tu >> 11;
    int c = lane & 15, q = lane >> 4;
    int row = gg * 128 + rt * 16 + c;
    float sc = (gg == 2) ? L2E2 : -L2E;
    const float* src = w_ih + (size_t)row * 128 + ks * 32 + q * 8;
    float4 a = *reinterpret_cast<const float4*>(src);
    float4 b = *reinterpret_cast<const float4*>(src + 4);
    a.x *= sc; a.y *= sc; a.z *= sc; a.w *= sc;
    b.x *= sc; b.y *= sc; b.z *= sc; b.w *= sc;
    bf16x8 p = pack8(a, b);
    *reinterpret_cast<u32x4*>(wpk + (size_t)tu * 4) = __builtin_bit_cast(u32x4, p);
}

// ------------- conv3 via MFMA : y2t[B,T,64] -> feat[B,T,128] ----------------
// GEMM M=128(co, 8 row-tiles), N=64 t/block (4 col-tiles), K=448 (14 ksteps).
// 512 thr = 8 waves; wave wv = row-tile wv, all 4 col-tiles. B from staged
// bf16 y2 tile (row pad 72 -> worst 2-way bank alias, free). BN scale folded
// in apk; bias+ReLU epilogue.
__global__ __launch_bounds__(512) void k_conv3m(
    const float* __restrict__ y2t, const unsigned* __restrict__ apk,
    const float* __restrict__ g, const float* __restrict__ bb,
    const float* __restrict__ m, const float* __restrict__ v,
    float* __restrict__ feat, int B, int T)
{
    __shared__ __align__(16) unsigned short yst[70 * 72];  // bf16, 9.8 KB
    const int b  = blockIdx.y;
    const int t0 = blockIdx.x * 64;
    const int tid = threadIdx.x;
    const int wv = tid >> 6;            // row-tile
    const int lane = tid & 63;
    const int c = lane & 15, q = lane >> 4;

    // stage 70 rows x 64 ci as bf16
    for (int i = tid; i < 70 * 8; i += 512) {
        int row = i >> 3, cg = (i & 7) * 8;
        int tg = t0 - 3 + row;
        bf16x8 p;
        if (tg >= 0 && tg < T) {
            const float* src = y2t + ((size_t)b * T + tg) * 64 + cg;
            float4 a0 = *reinterpret_cast<const float4*>(src);
            float4 a1 = *reinterpret_cast<const float4*>(src + 4);
            p = pack8(a0, a1);
        } else {
            u32x4 z = {0u, 0u, 0u, 0u};
            p = __builtin_bit_cast(bf16x8, z);
        }
        *reinterpret_cast<u32x4*>(&yst[row * 72 + cg]) = __builtin_bit_cast(u32x4, p);
    }
    __syncthreads();

    f32x4 acc[4] = {{0,0,0,0},{0,0,0,0},{0,0,0,0},{0,0,0,0}};
#pragma unroll
    for (int ks = 0; ks < 14; ++ks) {
        const int kk = ks >> 1, ci0 = (ks & 1) * 32 + q * 8;
        u32x4 au = *reinterpret_cast<const u32x4*>(
            apk + ((size_t)(wv * 14 + ks) * 64 + lane) * 4);
        bf16x8 av = __builtin_bit_cast(bf16x8, au);
#pragma unroll
        for (int nt = 0; nt < 4; ++nt) {
            u32x4 bu = *reinterpret_cast<const u32x4*>(
                &yst[(nt * 16 + c + kk) * 72 + ci0]);
            bf16x8 bv = __builtin_bit_cast(bf16x8, bu);
            acc[nt] = __builtin_amdgcn_mfma_f32_16x16x32_bf16(av, bv, acc[nt], 0, 0, 0);
        }
    }

    // epilogue: lane (c,q) -> col t=t0+nt*16+c, rows co0..co0+3
    const int co0 = wv * 16 + q * 4;
    float bf4[4];
#pragma unroll
    for (int r = 0; r < 4; ++r) {
        float sc = g[co0 + r] / sqrtf(v[co0 + r] + BN_EPS);
        bf4[r] = bb[co0 + r] - m[co0 + r] * sc;
    }
#pragma unroll
    for (int nt = 0; nt < 4; ++nt) {
        const int t = t0 + nt * 16 + c;
        float4 o;
        o.x = acc[nt][0] + bf4[0]; o.x = o.x > 0.f ? o.x : 0.f;
        o.y = acc[nt][1] + bf4[1]; o.y = o.y > 0.f ? o.y : 0.f;
        o.z = acc[nt][2] + bf4[2]; o.z = o.z > 0.f ? o.z : 0.f;
        o.w = acc[nt][3] + bf4[3]; o.w = o.w > 0.f ? o.w : 0.f;
        *reinterpret_cast<float4*>(feat + ((size_t)b * T + t) * 128 + co0) = o;
    }
}

// ----------- x-projection GEMM: xp = scale_g*(W_ih·x + b) (f16) -------------
// A from pre-packed wpk (scales folded) — no per-block pack8 VALU.
__global__ __launch_bounds__(256) void k_xpre(
    const float* __restrict__ feat, const unsigned* __restrict__ wpk,
    const float* __restrict__ b_ih, const float* __restrict__ b_hh,
    _Float16* __restrict__ xp, int T)
{
    const int b   = blockIdx.y;
    const int t0  = blockIdx.x * 32;
    const int tid = threadIdx.x;
    const int wv2 = tid >> 6;      // gate g
    const int lane = tid & 63;
    const int c2 = lane & 15;
    const int q2 = lane >> 4;
    const float sc = (wv2 == 2) ? L2E2 : -L2E;

    bf16x8 btile[2][4];
#pragma unroll
    for (int tc = 0; tc < 2; ++tc) {
        const float* xrow = feat + ((size_t)b * T + t0 + tc * 16 + c2) * 128;
#pragma unroll
        for (int ks = 0; ks < 4; ++ks) {
            float4 x0 = *reinterpret_cast<const float4*>(xrow + ks * 32 + q2 * 8);
            float4 x1 = *reinterpret_cast<const float4*>(xrow + ks * 32 + q2 * 8 + 4);
            btile[tc][ks] = pack8(x0, x1);
        }
    }

#pragma unroll
    for (int rt = 0; rt < 8; ++rt) {
        bf16x8 a[4];
#pragma unroll
        for (int ks = 0; ks < 4; ++ks) {
            u32x4 au = *reinterpret_cast<const u32x4*>(
                wpk + ((size_t)(((wv2 * 8 + rt) * 4 + ks) * 64) + lane) * 4);
            a[ks] = __builtin_bit_cast(bf16x8, au);
        }
        const int gr0 = wv2 * 128 + rt * 16 + q2 * 4;
        float4 bi = *reinterpret_cast<const float4*>(b_ih + gr0);
        float4 bh = *reinterpret_cast<const float4*>(b_hh + gr0);
        f32x4 bias = {(bi.x + bh.x) * sc, (bi.y + bh.y) * sc,
                      (bi.z + bh.z) * sc, (bi.w + bh.w) * sc};

#pragma unroll
        for (int tc = 0; tc < 2; ++tc) {
            f32x4 acc = bias;
#pragma unroll
            for (int ks = 0; ks < 4; ++ks)
                acc = __builtin_amdgcn_mfma_f32_16x16x32_bf16(a[ks], btile[tc][ks], acc, 0, 0, 0);
            const int t = t0 + tc * 16 + c2;
            f16x4 hv = {(_Float16)acc[0], (_Float16)acc[1],
                        (_Float16)acc[2], (_Float16)acc[3]};
            *reinterpret_cast<f16x4*>(
                xp + ((size_t)b * T + t) * 512 + (rt * 4 + q2) * 16 + wv2 * 4) = hv;
        }
    }
}

// --------------------- reversed-time LSTM (MFMA, K=128) ---------------------
// (unchanged from R13: 8 blocks x 8 batches, LBAR counted barrier)
#define SWZ(b) (((b) & 7) << 4)

#define LSTM_BODY(TCUR, RBUF, WBUF, Q0, Q1, PFT)                              \
    {                                                                          \
        f32x4 acc0 = {(float)Q0[0], (float)Q0[1], (float)Q0[2], (float)Q0[3]}; \
        f32x4 acc1 = {(float)Q0[4], (float)Q0[5], (float)Q0[6], (float)Q0[7]}; \
        f32x4 acc2 = {(float)Q1[0], (float)Q1[1], (float)Q1[2], (float)Q1[3]}; \
        f32x4 acc3 = {(float)Q1[4], (float)Q1[5], (float)Q1[6], (float)Q1[7]}; \
        const int pt_ = ((PFT) >= 0) ? (PFT) : 0;                              \
        Q0 = *reinterpret_cast<const f16x8*>(xpb + (size_t)pt_ * 512);         \
        Q1 = *reinterpret_cast<const f16x8*>(xpb + (size_t)pt_ * 512 + 8);     \
        const char* hrow_ = (const char*)&RBUF[c][0];                          \
        _Pragma("unroll")                                                      \
        for (int ks = 0; ks < 4; ++ks) {                                       \
            u32x4 bq = *reinterpret_cast<const u32x4*>(                        \
                hrow_ + ((ks * 64 + q * 16) ^ SWZ(c)));                        \
            bf16x8 bf = __builtin_bit_cast(bf16x8, bq);                        \
            acc0 = __builtin_amdgcn_mfma_f32_16x16x32_bf16(afr[0][ks], bf, acc0, 0, 0, 0); \
            acc1 = __builtin_amdgcn_mfma_f32_16x16x32_bf16(afr[1][ks], bf, acc1, 0, 0, 0); \
            acc2 = __builtin_amdgcn_mfma_f32_16x16x32_bf16(afr[2][ks], bf, acc2, 0, 0, 0); \
            acc3 = __builtin_amdgcn_mfma_f32_16x16x32_bf16(afr[3][ks], bf, acc3, 0, 0, 0); \
        }                                                                      \
        float h4_[4];                                                          \
        _Pragma("unroll")                                                      \
        for (int r = 0; r < 4; ++r) {                                          \
            float gi = rcp_f(1.0f + exp2_f(acc0[r]));                          \
            float gf = rcp_f(1.0f + exp2_f(acc1[r]));                          \
            float gg = fmaf(-2.0f, rcp_f(1.0f + exp2_f(acc2[r])), 1.0f);       \
            float go = rcp_f(1.0f + exp2_f(acc3[r]));                          \
            cst[r] = fmaf(gf, cst[r], gi * gg);                                \
            float tc_ = fmaf(-2.0f, rcp_f(1.0f + exp2_f(cst[r] * L2E2)), 1.0f);\
            h4_[r] = go * tc_;                                                 \
        }                                                                      \
        if (valid) {                                                           \
            *reinterpret_cast<float4*>(out + ((size_t)b * T + (TCUR)) * 128 + u0) = \
                make_float4(h4_[0], h4_[1], h4_[2], h4_[3]);                   \
            u32x2 hw_;                                                         \
            hw_.x = cvtpk_bf16(h4_[0], h4_[1]);                                \
            hw_.y = cvtpk_bf16(h4_[2], h4_[3]);                                \
            *reinterpret_cast<u32x2*>(                                         \
                (char*)&WBUF[c][0] + ((u0 * 2) ^ SWZ(c))) = hw_;               \
        }                                                                      \
    }

__global__ __launch_bounds__(512) void k_lstm7(
    const _Float16* __restrict__ xp, const float* __restrict__ w_hh,
    float* __restrict__ out, int T)
{
    __shared__ __align__(16) unsigned short h_lds[2][16][128];  // bf16, 8 KB

    const int tid  = threadIdx.x;
    const int bk   = blockIdx.x;          // batches [bk*8, bk*8+8)
    const int wv   = tid >> 6;
    const int lane = tid & 63;
    const int c    = lane & 15;
    const int q    = lane >> 4;
    const int u0   = wv * 16 + q * 4;
    const bool valid = (c < 8);
    const int b    = bk * 8 + (c & 7);    // clamped for invalid lanes

    bf16x8 afr[4][4];
#pragma unroll
    for (int g = 0; g < 4; ++g) {
        const float sc = (g == 2) ? L2E2 : -L2E;
        const float* wr = w_hh + (size_t)(g * 128 + wv * 16 + c) * 128;
#pragma unroll
        for (int ks = 0; ks < 4; ++ks) {
            float4 w0 = *reinterpret_cast<const float4*>(wr + ks * 32 + q * 8);
            float4 w1 = *reinterpret_cast<const float4*>(wr + ks * 32 + q * 8 + 4);
            w0.x *= sc; w0.y *= sc; w0.z *= sc; w0.w *= sc;
            w1.x *= sc; w1.y *= sc; w1.z *= sc; w1.w *= sc;
            afr[g][ks] = pack8(w0, w1);
        }
    }

    {
        u32x2 z = {0u, 0u};
        *reinterpret_cast<u32x2*>((char*)&h_lds[0][c][0] + ((u0 * 2) ^ SWZ(c))) = z;
        *reinterpret_cast<u32x2*>((char*)&h_lds[1][c][0] + ((u0 * 2) ^ SWZ(c))) = z;
    }
    f32x4 cst = {0.f, 0.f, 0.f, 0.f};

    const _Float16* xpb = xp + ((size_t)b * T) * 512 + (wv * 4 + q) * 16;
    f16x8 PA0 = *reinterpret_cast<const f16x8*>(xpb + (size_t)(T - 1) * 512);
    f16x8 PA1 = *reinterpret_cast<const f16x8*>(xpb + (size_t)(T - 1) * 512 + 8);
    f16x8 PB0 = *reinterpret_cast<const f16x8*>(xpb + (size_t)(T - 2) * 512);
    f16x8 PB1 = *reinterpret_cast<const f16x8*>(xpb + (size_t)(T - 2) * 512 + 8);
    __syncthreads();

    for (int t = T - 1; t > 0; t -= 2) {
        LSTM_BODY(t,     h_lds[0], h_lds[1], PA0, PA1, t - 2);
        LBAR();
        LSTM_BODY(t - 1, h_lds[1], h_lds[0], PB0, PB1, t - 3);
        LBAR();
    }
}

// ------------------- fallback LSTM (K=256 interleaved) ----------------------
__global__ __launch_bounds__(512) void k_lstm4(
    const float* __restrict__ feat, const float* __restrict__ w_ih,
    const float* __restrict__ w_hh, const float* __restrict__ b_ih,
    const float* __restrict__ b_hh, float* __restrict__ out, int T)
{
    __shared__ __align__(16) unsigned hx[2][16][128];
    __shared__ __align__(16) u32x4 wlds[8 * 2 * 8 * 64];

    const int tid  = threadIdx.x;
    const int bk   = blockIdx.x;
    const int wv   = tid >> 6;
    const int lane = tid & 63;
    const int c    = lane & 15;
    const int q    = lane >> 4;

    bf16x8 afr[2][8];
#pragma unroll
    for (int g = 0; g < 4; ++g) {
        const int row = g * 128 + wv * 16 + c;
#pragma unroll
        for (int ks = 0; ks < 8; ++ks) {
            const int m0 = ks * 16 + q * 4;
            float4 h4 = *reinterpret_cast<const float4*>(w_hh + (size_t)row * 128 + m0);
            float4 i4 = *reinterpret_cast<const float4*>(w_ih + (size_t)row * 128 + m0);
            u32x4 u;
            u.x = (bfr(i4.x) << 16) | bfr(h4.x);
            u.y = (bfr(i4.y) << 16) | bfr(h4.y);
            u.z = (bfr(i4.z) << 16) | bfr(h4.z);
            u.w = (bfr(i4.w) << 16) | bfr(h4.w);
            if (g < 2)
                afr[g][ks] = __builtin_bit_cast(bf16x8, u);
            else
                wlds[((wv * 2 + (g - 2)) * 8 + ks) * 64 + lane] = u;
        }
    }

    float bias[4][4];
#pragma unroll
    for (int g = 0; g < 4; ++g)
#pragma unroll
        for (int r = 0; r < 4; ++r) {
            const int j = wv * 16 + q * 4 + r;
            bias[g][r] = b_ih[g * 128 + j] + b_hh[g * 128 + j];
        }

    const size_t fbase = ((size_t)(bk * 16 + c)) * T;
    const int u0 = wv * 16 + q * 4;

    {
        float4 x0 = *reinterpret_cast<const float4*>(feat + (fbase + (T - 1)) * 128 + u0);
        u32x4 u;
        u.x = bfr(x0.x) << 16;
        u.y = bfr(x0.y) << 16;
        u.z = bfr(x0.z) << 16;
        u.w = bfr(x0.w) << 16;
        *reinterpret_cast<u32x4*>((char*)&hx[0][c][0] + ((u0 * 4) ^ SWZ(c))) = u;
    }
    f32x4 cst = {0.f, 0.f, 0.f, 0.f};
    __syncthreads();

    int cur = 0;
    for (int t = T - 1; t >= 0; --t) {
        const int tp = (t > 0) ? t - 1 : 0;
        float4 xpv = *reinterpret_cast<const float4*>(feat + (fbase + tp) * 128 + u0);

        f32x4 acc0 = {bias[0][0], bias[0][1], bias[0][2], bias[0][3]};
        f32x4 acc1 = {bias[1][0], bias[1][1], bias[1][2], bias[1][3]};
        f32x4 acc2 = {bias[2][0], bias[2][1], bias[2][2], bias[2][3]};
        f32x4 acc3 = {bias[3][0], bias[3][1], bias[3][2], bias[3][3]};

        const char* hrow = (const char*)&hx[cur][c][0];
        const u32x4* wp0 = &wlds[(wv * 2 + 0) * 8 * 64 + lane];
        const u32x4* wp1 = &wlds[(wv * 2 + 1) * 8 * 64 + lane];
#pragma unroll
        for (int ks = 0; ks < 8; ++ks) {
            u32x4 bq = *reinterpret_cast<const u32x4*>(
                hrow + ((ks * 64 + q * 16) ^ SWZ(c)));
            bf16x8 bf = __builtin_bit_cast(bf16x8, bq);
            acc0 = __builtin_amdgcn_mfma_f32_16x16x32_bf16(afr[0][ks], bf, acc0, 0, 0, 0);
            acc1 = __builtin_amdgcn_mfma_f32_16x16x32_bf16(afr[1][ks], bf, acc1, 0, 0, 0);
            bf16x8 a2 = __builtin_bit_cast(bf16x8, wp0[ks * 64]);
            acc2 = __builtin_amdgcn_mfma_f32_16x16x32_bf16(a2, bf, acc2, 0, 0, 0);
            bf16x8 a3 = __builtin_bit_cast(bf16x8, wp1[ks * 64]);
            acc3 = __builtin_amdgcn_mfma_f32_16x16x32_bf16(a3, bf, acc3, 0, 0, 0);
        }

        float h[4];
#pragma unroll
        for (int r = 0; r < 4; ++r) {
            float gi = sigf(acc0[r]);
            float gf = sigf(acc1[r]);
            float gg = tanhfast(acc2[r]);
            float go = sigf(acc3[r]);
            cst[r] = gf * cst[r] + gi * gg;
            h[r] = go * tanhfast(cst[r]);
        }
        *reinterpret_cast<float4*>(out + (fbase + t) * 128 + u0) =
            make_float4(h[0], h[1], h[2], h[3]);

        u32x4 u;
        u.x = (bfr(xpv.x) << 16) | bfr(h[0]);
        u.y = (bfr(xpv.y) << 16) | bfr(h[1]);
        u.z = (bfr(xpv.z) << 16) | bfr(h[2]);
        u.w = (bfr(xpv.w) << 16) | bfr(h[3]);
        *reinterpret_cast<u32x4*>((char*)&hx[cur ^ 1][c][0] + ((u0 * 4) ^ SWZ(c))) = u;

        cur ^= 1;
        __syncthreads();
    }
}

extern "C" void kernel_launch(void* const* d_in, const int* in_sizes, int n_in,
                              void* d_out, int out_size, void* d_ws, size_t ws_size,
                              hipStream_t stream)
{
    const float* x    = (const float*)d_in[0];
    const float* c1w  = (const float*)d_in[1];
    const float* bn1g = (const float*)d_in[2];
    const float* bn1b = (const float*)d_in[3];
    const float* bn1m = (const float*)d_in[4];
    const float* bn1v = (const float*)d_in[5];
    const float* c2w  = (const float*)d_in[6];
    const float* bn2g = (const float*)d_in[7];
    const float* bn2b = (const float*)d_in[8];
    const float* bn2m = (const float*)d_in[9];
    const float* bn2v = (const float*)d_in[10];
    const float* c3w  = (const float*)d_in[11];
    const float* bn3g = (const float*)d_in[12];
    const float* bn3b = (const float*)d_in[13];
    const float* bn3m = (const float*)d_in[14];
    const float* bn3v = (const float*)d_in[15];
    const float* w_ih = (const float*)d_in[16];
    const float* w_hh = (const float*)d_in[17];
    const float* b_ih = (const float*)d_in[18];
    const float* b_hh = (const float*)d_in[19];
    float* out = (float*)d_out;

    const int B = 64, T = 4096;
    char* ws = (char*)d_ws;
    const size_t sz_y1 = (size_t)B * 32 * T * 4;        //  32 MB
    const size_t sz_y2 = (size_t)B * 64 * T * 4;        //  64 MB
    const size_t sz_xp = (size_t)B * T * 512 * 2;       // 256 MB (f16)

    const bool fast = ws_size >= sz_y2 + sz_xp;         // 320 MB

    if (fast) {
        float* y1    = (float*)d_out;            // d_out scratch (dead later)
        float* y2t   = (float*)ws;               // ws[0, 64MB), t-major
        float* feat  = (float*)d_out;            // d_out reused (y1 dead)
        _Float16* xp = (_Float16*)(ws + sz_y2);  // ws[64, 320MB)
        unsigned* apk = (unsigned*)(ws + sz_y2); // 112KB, dead before xp write
        unsigned* wpk = (unsigned*)ws;           // 128KB, overwrites y2t head
                                                 // AFTER conv3m is done

        k_pack_w3<<<dim3(28), 256, 0, stream>>>(c3w, bn3g, bn3v, apk);
        k_conv1<<<dim3(T / 256, B), 256, 0, stream>>>(x, c1w, bn1g, bn1b, bn1m, bn1v, y1, B, T);
        k_conv2<<<dim3(T / 256, B), 256, 0, stream>>>(y1, c2w, bn2g, bn2b, bn2m, bn2v, y2t, B, T);
        k_conv3m<<<dim3(T / 64, B), 512, 0, stream>>>(y2t, apk, bn3g, bn3b, bn3m, bn3v, feat, B, T);
        k_pack_wih<<<dim3(32), 256, 0, stream>>>(w_ih, wpk);
        k_xpre<<<dim3(T / 32, B), 256, 0, stream>>>(feat, wpk, b_ih, b_hh, xp, T);
        k_lstm7<<<dim3(8), 512, 0, stream>>>(xp, w_hh, out, T);
    } else {
        float* y1   = (float*)ws;
        float* y2t  = (float*)(ws + sz_y1);
        float* feat = (float*)(ws + sz_y1 + sz_y2);
        unsigned* apk = (unsigned*)ws;           // y1 region, dead after conv2

        k_conv1<<<dim3(T / 256, B), 256, 0, stream>>>(x, c1w, bn1g, bn1b, bn1m, bn1v, y1, B, T);
        k_conv2<<<dim3(T / 256, B), 256, 0, stream>>>(y1, c2w, bn2g, bn2b, bn2m, bn2v, y2t, B, T);
        k_pack_w3<<<dim3(28), 256, 0, stream>>>(c3w, bn3g, bn3v, apk);
        k_conv3m<<<dim3(T / 64, B), 512, 0, stream>>>(y2t, apk, bn3g, bn3b, bn3m, bn3v, feat, B, T);
        k_lstm4<<<dim3(4), 512, 0, stream>>>(feat, w_ih, w_hh, b_ih, b_hh, out, T);
    }
}